// Round 1
// baseline (766.779 us; speedup 1.0000x reference)
//
#include <hip/hip_runtime.h>
#include <hip/hip_bf16.h>

#define IN_DIM 128
#define HID1 256
#define HID2 128

// ---------------------------------------------------------------- histogram
__global__ void hist_kernel(const int* __restrict__ src, const int* __restrict__ dst,
                            int* __restrict__ deg_out, int* __restrict__ deg_in, int E) {
    int e = blockIdx.x * blockDim.x + threadIdx.x;
    if (e < E) {
        atomicAdd(&deg_out[src[e]], 1);
        atomicAdd(&deg_in[dst[e]], 1);
    }
}

// ---------------------------------------------------------------- inv degree
__global__ void inv_kernel(const int* __restrict__ deg_in, const int* __restrict__ deg_out,
                           float* __restrict__ inv_i, float* __restrict__ inv_o, int n) {
    int i = blockIdx.x * blockDim.x + threadIdx.x;
    if (i < n) {
        inv_i[i] = 1.0f / sqrtf((float)max(deg_in[i], 1));
        inv_o[i] = 1.0f / sqrtf((float)max(deg_out[i], 1));
    }
}

// ---------------------------------------------------------------- exclusive scan (single block)
__global__ __launch_bounds__(1024) void scan_kernel(const int* __restrict__ deg,
                                                    int* __restrict__ row,
                                                    int* __restrict__ cursor, int n) {
    __shared__ int smem[1024];
    int tid = threadIdx.x;
    int chunk = (n + 1023) >> 10;
    int beg = tid * chunk;
    int end = min(beg + chunk, n);
    int s = 0;
    for (int i = beg; i < end; ++i) s += deg[i];
    smem[tid] = s;
    __syncthreads();
    // Hillis-Steele inclusive scan
    for (int off = 1; off < 1024; off <<= 1) {
        int v = (tid >= off) ? smem[tid - off] : 0;
        __syncthreads();
        smem[tid] += v;
        __syncthreads();
    }
    int excl = smem[tid] - s;
    int running = excl;
    for (int i = beg; i < end; ++i) {
        row[i] = running;
        cursor[i] = running;
        running += deg[i];
    }
    if (tid == 1023) row[n] = smem[1023];
}

// ---------------------------------------------------------------- scatter into CSR
__global__ void scatter_kernel(const int* __restrict__ src, const int* __restrict__ dst,
                               int* __restrict__ cursor, int* __restrict__ csr_src, int E) {
    int e = blockIdx.x * blockDim.x + threadIdx.x;
    if (e < E) {
        int p = atomicAdd(&cursor[dst[e]], 1);
        csr_src[p] = src[e];
    }
}

// ---------------------------------------------------------------- node-parallel CSR SpMM (F=128)
// out[i][f] = sum_{j in row[i]..row[i+1]} feat[csr_src[j]][f] * (scale ? scale[csr_src[j]] : 1)
__global__ __launch_bounds__(128) void spmm_kernel(const float* __restrict__ feat,
                                                   const float* __restrict__ scale,
                                                   const int* __restrict__ row,
                                                   const int* __restrict__ csr_src,
                                                   float* __restrict__ out) {
    const int i = blockIdx.x;
    const int f = threadIdx.x;
    const int beg = row[i];
    const int end = row[i + 1];
    float acc = 0.f;
    int j = beg;
    if (scale) {
        for (; j + 4 <= end; j += 4) {
            int s0 = csr_src[j], s1 = csr_src[j + 1], s2 = csr_src[j + 2], s3 = csr_src[j + 3];
            float c0 = scale[s0], c1 = scale[s1], c2 = scale[s2], c3 = scale[s3];
            acc += feat[(size_t)s0 * IN_DIM + f] * c0;
            acc += feat[(size_t)s1 * IN_DIM + f] * c1;
            acc += feat[(size_t)s2 * IN_DIM + f] * c2;
            acc += feat[(size_t)s3 * IN_DIM + f] * c3;
        }
        for (; j < end; ++j) {
            int s0 = csr_src[j];
            acc += feat[(size_t)s0 * IN_DIM + f] * scale[s0];
        }
    } else {
        for (; j + 4 <= end; j += 4) {
            int s0 = csr_src[j], s1 = csr_src[j + 1], s2 = csr_src[j + 2], s3 = csr_src[j + 3];
            acc += feat[(size_t)s0 * IN_DIM + f];
            acc += feat[(size_t)s1 * IN_DIM + f];
            acc += feat[(size_t)s2 * IN_DIM + f];
            acc += feat[(size_t)s3 * IN_DIM + f];
        }
        for (; j < end; ++j) acc += feat[(size_t)csr_src[j] * IN_DIM + f];
    }
    out[(size_t)i * IN_DIM + f] = acc;
}

// ---------------------------------------------------------------- tiled fp32 GEMM with fused
// row-scale on A, bias, relu, row-scale on output.
// C[r][c] = ((sum_k A[r][k]*scaleA[r]*B[k][c]) + bias[c]) -> relu? -> * scaleOut[r]
#define TBM 64
#define TBN 64
#define TBK 32
__global__ __launch_bounds__(256) void sgemm_kernel(const float* __restrict__ A,
                                                    const float* __restrict__ B,
                                                    float* __restrict__ C,
                                                    const float* __restrict__ scaleA,
                                                    const float* __restrict__ bias,
                                                    const float* __restrict__ scaleOut,
                                                    int M, int N, int K, int doRelu) {
    __shared__ float As[TBK][TBM + 4];  // +4 keeps 16B alignment, breaks bank stride
    __shared__ float Bs[TBK][TBN];
    const int tid = threadIdx.x;
    const int bm = blockIdx.x * TBM;
    const int bn = blockIdx.y * TBN;
    const int tr = (tid >> 4) << 2;  // row offset in tile, 0..60
    const int tc = (tid & 15) << 2;  // col offset in tile, 0..60
    float acc[4][4] = {};

    for (int k0 = 0; k0 < K; k0 += TBK) {
        // load A tile 64x32 (transposed into LDS), 2 float4 per thread
#pragma unroll
        for (int i = 0; i < 2; ++i) {
            int slot = tid + (i << 8);
            int r = slot >> 3;
            int c = (slot & 7) << 2;
            int grow = bm + r;
            float4 v = make_float4(0.f, 0.f, 0.f, 0.f);
            if (grow < M) {
                v = *reinterpret_cast<const float4*>(A + (size_t)grow * K + k0 + c);
                if (scaleA) {
                    float s = scaleA[grow];
                    v.x *= s; v.y *= s; v.z *= s; v.w *= s;
                }
            }
            As[c + 0][r] = v.x;
            As[c + 1][r] = v.y;
            As[c + 2][r] = v.z;
            As[c + 3][r] = v.w;
        }
        // load B tile 32x64, 2 float4 per thread
#pragma unroll
        for (int i = 0; i < 2; ++i) {
            int slot = tid + (i << 8);
            int r = slot >> 4;
            int c = (slot & 15) << 2;
            float4 v = *reinterpret_cast<const float4*>(B + (size_t)(k0 + r) * N + bn + c);
            *reinterpret_cast<float4*>(&Bs[r][c]) = v;
        }
        __syncthreads();
#pragma unroll
        for (int kk = 0; kk < TBK; ++kk) {
            float4 a = *reinterpret_cast<const float4*>(&As[kk][tr]);
            float4 b = *reinterpret_cast<const float4*>(&Bs[kk][tc]);
            acc[0][0] += a.x * b.x; acc[0][1] += a.x * b.y; acc[0][2] += a.x * b.z; acc[0][3] += a.x * b.w;
            acc[1][0] += a.y * b.x; acc[1][1] += a.y * b.y; acc[1][2] += a.y * b.z; acc[1][3] += a.y * b.w;
            acc[2][0] += a.z * b.x; acc[2][1] += a.z * b.y; acc[2][2] += a.z * b.z; acc[2][3] += a.z * b.w;
            acc[3][0] += a.w * b.x; acc[3][1] += a.w * b.y; acc[3][2] += a.w * b.z; acc[3][3] += a.w * b.w;
        }
        __syncthreads();
    }

    float bv[4] = {0.f, 0.f, 0.f, 0.f};
    if (bias) {
        bv[0] = bias[bn + tc + 0];
        bv[1] = bias[bn + tc + 1];
        bv[2] = bias[bn + tc + 2];
        bv[3] = bias[bn + tc + 3];
    }
#pragma unroll
    for (int i = 0; i < 4; ++i) {
        int r = bm + tr + i;
        if (r < M) {
            float so = scaleOut ? scaleOut[r] : 1.f;
            float4 o;
            o.x = acc[i][0] + bv[0];
            o.y = acc[i][1] + bv[1];
            o.z = acc[i][2] + bv[2];
            o.w = acc[i][3] + bv[3];
            if (doRelu) {
                o.x = fmaxf(o.x, 0.f); o.y = fmaxf(o.y, 0.f);
                o.z = fmaxf(o.z, 0.f); o.w = fmaxf(o.w, 0.f);
            }
            o.x *= so; o.y *= so; o.z *= so; o.w *= so;
            *reinterpret_cast<float4*>(C + (size_t)r * N + bn + tc) = o;
        }
    }
}

// ---------------------------------------------------------------- per-graph mean pool with
// fused layer-2 epilogue: hg[g][f] = mean_i relu(agg2[i][f]*inv_i[i] + b2[f])
__device__ __forceinline__ int lower_bound_i(const int* a, int n, int key) {
    int lo = 0, hi = n;
    while (lo < hi) {
        int mid = (lo + hi) >> 1;
        if (a[mid] < key) lo = mid + 1; else hi = mid;
    }
    return lo;
}

__global__ __launch_bounds__(128) void pool_kernel(const float* __restrict__ agg2,
                                                   const float* __restrict__ inv_i,
                                                   const float* __restrict__ b2,
                                                   const int* __restrict__ graph_id,
                                                   int n, float* __restrict__ hg) {
    const int g = blockIdx.x;
    const int f = threadIdx.x;
    __shared__ int sh[2];
    if (f == 0) {
        sh[0] = lower_bound_i(graph_id, n, g);
        sh[1] = lower_bound_i(graph_id, n, g + 1);
    }
    __syncthreads();
    const int beg = sh[0], end = sh[1];
    const float bias = b2[f];
    float acc = 0.f;
    for (int i = beg; i < end; ++i) {
        float v = agg2[(size_t)i * HID2 + f] * inv_i[i] + bias;
        acc += (v > 0.f) ? v : 0.f;
    }
    float cnt = (float)(end - beg);
    if (cnt < 1.f) cnt = 1.f;
    hg[g * HID2 + f] = acc / cnt;
}

// ---------------------------------------------------------------- tiny 3-layer MLP, block/graph
__global__ __launch_bounds__(64) void mlp_kernel(const float* __restrict__ hg,
                                                 const float* __restrict__ Wc1, const float* __restrict__ bc1,
                                                 const float* __restrict__ Wc2, const float* __restrict__ bc2,
                                                 const float* __restrict__ Wc3, const float* __restrict__ bc3,
                                                 float* __restrict__ out) {
    const int g = blockIdx.x;
    const int t = threadIdx.x;
    __shared__ float h[HID2];
    __shared__ float t1[12];
    __shared__ float t2[12];
    for (int i = t; i < HID2; i += 64) h[i] = hg[g * HID2 + i];
    __syncthreads();
    if (t < 12) {
        float a = bc1[t];
        for (int k = 0; k < HID2; ++k) a += h[k] * Wc1[k * 12 + t];
        t1[t] = a;
    }
    __syncthreads();
    if (t < 12) {
        float a = bc2[t];
        for (int k = 0; k < 12; ++k) a += t1[k] * Wc2[k * 12 + t];
        t2[t] = a;
    }
    __syncthreads();
    if (t < 10) {
        float a = bc3[t];
        for (int k = 0; k < 12; ++k) a += t2[k] * Wc3[k * 10 + t];
        out[g * 10 + t] = a;
    }
}

// ================================================================ launch
extern "C" void kernel_launch(void* const* d_in, const int* in_sizes, int n_in,
                              void* d_out, int out_size, void* d_ws, size_t ws_size,
                              hipStream_t stream) {
    const float* x        = (const float*)d_in[0];
    const int*   src      = (const int*)d_in[1];
    const int*   dst      = (const int*)d_in[2];
    const int*   graph_id = (const int*)d_in[3];
    const float* W1       = (const float*)d_in[4];
    const float* b1       = (const float*)d_in[5];
    const float* W2       = (const float*)d_in[6];
    const float* b2       = (const float*)d_in[7];
    const float* Wc1      = (const float*)d_in[8];
    const float* bc1      = (const float*)d_in[9];
    const float* Wc2      = (const float*)d_in[10];
    const float* bc2      = (const float*)d_in[11];
    const float* Wc3      = (const float*)d_in[12];
    const float* bc3      = (const float*)d_in[13];
    float* out = (float*)d_out;

    const int N = in_sizes[0] / IN_DIM;   // 50000
    const int E = in_sizes[1];            // 800000
    const int G = out_size / 10;          // 64

    char* ws = (char*)d_ws;
    size_t off = 0;
    auto alloc = [&](size_t bytes) -> char* {
        char* p = ws + off;
        off = (off + bytes + 255) & ~(size_t)255;
        return p;
    };
    int*   deg_in  = (int*)alloc((size_t)N * 4);
    int*   deg_out = (int*)alloc((size_t)N * 4);
    float* inv_i   = (float*)alloc((size_t)N * 4);
    float* inv_o   = (float*)alloc((size_t)N * 4);
    int*   row     = (int*)alloc((size_t)(N + 1) * 4);
    int*   cursor  = (int*)alloc((size_t)N * 4);
    int*   csr_src = (int*)alloc((size_t)E * 4);
    float* hg      = (float*)alloc((size_t)G * HID2 * 4);
    float* agg1    = (float*)alloc((size_t)N * IN_DIM * 4);   // reused as agg2
    float* h1      = (float*)alloc((size_t)N * HID1 * 4);
    float* xw2     = (float*)alloc((size_t)N * HID2 * 4);
    float* agg2 = agg1;

    hipMemsetAsync(deg_in, 0, (size_t)N * 4, stream);
    hipMemsetAsync(deg_out, 0, (size_t)N * 4, stream);

    hist_kernel<<<(E + 255) / 256, 256, 0, stream>>>(src, dst, deg_out, deg_in, E);
    inv_kernel<<<(N + 255) / 256, 256, 0, stream>>>(deg_in, deg_out, inv_i, inv_o, N);
    scan_kernel<<<1, 1024, 0, stream>>>(deg_in, row, cursor, N);
    scatter_kernel<<<(E + 255) / 256, 256, 0, stream>>>(src, dst, cursor, csr_src, E);

    // Layer 1, aggregate-first: agg1 = A * (x * inv_o); h1 = relu(inv_i*agg1 @ W1 + b1) * inv_o
    spmm_kernel<<<N, 128, 0, stream>>>(x, inv_o, row, csr_src, agg1);
    sgemm_kernel<<<dim3((N + TBM - 1) / TBM, HID1 / TBN), 256, 0, stream>>>(
        agg1, W1, h1, inv_i, b1, inv_o, N, HID1, IN_DIM, 1);

    // Layer 2, weight-first: xw2 = h1 @ W2 (h1 already carries inv_o); agg2 = A * xw2
    sgemm_kernel<<<dim3((N + TBM - 1) / TBM, HID2 / TBN), 256, 0, stream>>>(
        h1, W2, xw2, nullptr, nullptr, nullptr, N, HID2, HID1, 0);
    spmm_kernel<<<N, 128, 0, stream>>>(xw2, nullptr, row, csr_src, agg2);

    // Pool (fused relu(agg2*inv_i+b2)) + MLP
    pool_kernel<<<G, 128, 0, stream>>>(agg2, inv_i, b2, graph_id, N, hg);
    mlp_kernel<<<G, 64, 0, stream>>>(hg, Wc1, bc1, Wc2, bc2, Wc3, bc3, out);
}

// Round 2
// 574.086 us; speedup vs baseline: 1.3357x; 1.3357x over previous
//
#include <hip/hip_runtime.h>
#include <hip/hip_bf16.h>

#define IN_DIM 128
#define HID1 256
#define HID2 128

// ---------------------------------------------------------------- histogram
__global__ void hist_kernel(const int* __restrict__ src, const int* __restrict__ dst,
                            int* __restrict__ deg_out, int* __restrict__ deg_in, int E) {
    int e = blockIdx.x * blockDim.x + threadIdx.x;
    if (e < E) {
        atomicAdd(&deg_out[src[e]], 1);
        atomicAdd(&deg_in[dst[e]], 1);
    }
}

// ---------------------------------------------------------------- inv degree
__global__ void inv_kernel(const int* __restrict__ deg_in, const int* __restrict__ deg_out,
                           float* __restrict__ inv_i, float* __restrict__ inv_o, int n) {
    int i = blockIdx.x * blockDim.x + threadIdx.x;
    if (i < n) {
        inv_i[i] = 1.0f / sqrtf((float)max(deg_in[i], 1));
        inv_o[i] = 1.0f / sqrtf((float)max(deg_out[i], 1));
    }
}

// ---------------------------------------------------------------- exclusive scan (single block)
__global__ __launch_bounds__(1024) void scan_kernel(const int* __restrict__ deg,
                                                    int* __restrict__ row,
                                                    int* __restrict__ cursor, int n) {
    __shared__ int smem[1024];
    int tid = threadIdx.x;
    int chunk = (n + 1023) >> 10;
    int beg = tid * chunk;
    int end = min(beg + chunk, n);
    int s = 0;
    for (int i = beg; i < end; ++i) s += deg[i];
    smem[tid] = s;
    __syncthreads();
    // Hillis-Steele inclusive scan
    for (int off = 1; off < 1024; off <<= 1) {
        int v = (tid >= off) ? smem[tid - off] : 0;
        __syncthreads();
        smem[tid] += v;
        __syncthreads();
    }
    int excl = smem[tid] - s;
    int running = excl;
    for (int i = beg; i < end; ++i) {
        row[i] = running;
        cursor[i] = running;
        running += deg[i];
    }
    if (tid == 1023) row[n] = smem[1023];
}

// ---------------------------------------------------------------- scatter into CSR
__global__ void scatter_kernel(const int* __restrict__ src, const int* __restrict__ dst,
                               int* __restrict__ cursor, int* __restrict__ csr_src, int E) {
    int e = blockIdx.x * blockDim.x + threadIdx.x;
    if (e < E) {
        int p = atomicAdd(&cursor[dst[e]], 1);
        csr_src[p] = src[e];
    }
}

// ---------------------------------------------------------------- node-parallel CSR SpMM (F=128)
// out[i][f] = sum_{j in row[i]..row[i+1]} feat[csr_src[j]][f] * (scale ? scale[csr_src[j]] : 1)
__global__ __launch_bounds__(128) void spmm_kernel(const float* __restrict__ feat,
                                                   const float* __restrict__ scale,
                                                   const int* __restrict__ row,
                                                   const int* __restrict__ csr_src,
                                                   float* __restrict__ out) {
    const int i = blockIdx.x;
    const int f = threadIdx.x;
    const int beg = row[i];
    const int end = row[i + 1];
    float acc = 0.f;
    int j = beg;
    if (scale) {
        for (; j + 4 <= end; j += 4) {
            int s0 = csr_src[j], s1 = csr_src[j + 1], s2 = csr_src[j + 2], s3 = csr_src[j + 3];
            float c0 = scale[s0], c1 = scale[s1], c2 = scale[s2], c3 = scale[s3];
            acc += feat[(size_t)s0 * IN_DIM + f] * c0;
            acc += feat[(size_t)s1 * IN_DIM + f] * c1;
            acc += feat[(size_t)s2 * IN_DIM + f] * c2;
            acc += feat[(size_t)s3 * IN_DIM + f] * c3;
        }
        for (; j < end; ++j) {
            int s0 = csr_src[j];
            acc += feat[(size_t)s0 * IN_DIM + f] * scale[s0];
        }
    } else {
        for (; j + 4 <= end; j += 4) {
            int s0 = csr_src[j], s1 = csr_src[j + 1], s2 = csr_src[j + 2], s3 = csr_src[j + 3];
            acc += feat[(size_t)s0 * IN_DIM + f];
            acc += feat[(size_t)s1 * IN_DIM + f];
            acc += feat[(size_t)s2 * IN_DIM + f];
            acc += feat[(size_t)s3 * IN_DIM + f];
        }
        for (; j < end; ++j) acc += feat[(size_t)csr_src[j] * IN_DIM + f];
    }
    out[(size_t)i * IN_DIM + f] = acc;
}

// ---------------------------------------------------------------- tiled fp32 GEMM with fused
// row-scale on A, bias, relu, row-scale on output.
// C[r][c] = ((sum_k A[r][k]*scaleA[r]*B[k][c]) + bias[c]) -> relu? -> * scaleOut[r]
#define TBM 64
#define TBN 64
#define TBK 32
__global__ __launch_bounds__(256) void sgemm_kernel(const float* __restrict__ A,
                                                    const float* __restrict__ B,
                                                    float* __restrict__ C,
                                                    const float* __restrict__ scaleA,
                                                    const float* __restrict__ bias,
                                                    const float* __restrict__ scaleOut,
                                                    int M, int N, int K, int doRelu) {
    __shared__ float As[TBK][TBM + 4];  // +4 keeps 16B alignment, breaks bank stride
    __shared__ float Bs[TBK][TBN];
    const int tid = threadIdx.x;
    const int bm = blockIdx.x * TBM;
    const int bn = blockIdx.y * TBN;
    const int tr = (tid >> 4) << 2;  // row offset in tile, 0..60
    const int tc = (tid & 15) << 2;  // col offset in tile, 0..60
    float acc[4][4] = {};

    for (int k0 = 0; k0 < K; k0 += TBK) {
        // load A tile 64x32 (transposed into LDS), 2 float4 per thread
#pragma unroll
        for (int i = 0; i < 2; ++i) {
            int slot = tid + (i << 8);
            int r = slot >> 3;
            int c = (slot & 7) << 2;
            int grow = bm + r;
            float4 v = make_float4(0.f, 0.f, 0.f, 0.f);
            if (grow < M) {
                v = *reinterpret_cast<const float4*>(A + (size_t)grow * K + k0 + c);
                if (scaleA) {
                    float s = scaleA[grow];
                    v.x *= s; v.y *= s; v.z *= s; v.w *= s;
                }
            }
            As[c + 0][r] = v.x;
            As[c + 1][r] = v.y;
            As[c + 2][r] = v.z;
            As[c + 3][r] = v.w;
        }
        // load B tile 32x64, 2 float4 per thread
#pragma unroll
        for (int i = 0; i < 2; ++i) {
            int slot = tid + (i << 8);
            int r = slot >> 4;
            int c = (slot & 15) << 2;
            float4 v = *reinterpret_cast<const float4*>(B + (size_t)(k0 + r) * N + bn + c);
            *reinterpret_cast<float4*>(&Bs[r][c]) = v;
        }
        __syncthreads();
#pragma unroll
        for (int kk = 0; kk < TBK; ++kk) {
            float4 a = *reinterpret_cast<const float4*>(&As[kk][tr]);
            float4 b = *reinterpret_cast<const float4*>(&Bs[kk][tc]);
            acc[0][0] += a.x * b.x; acc[0][1] += a.x * b.y; acc[0][2] += a.x * b.z; acc[0][3] += a.x * b.w;
            acc[1][0] += a.y * b.x; acc[1][1] += a.y * b.y; acc[1][2] += a.y * b.z; acc[1][3] += a.y * b.w;
            acc[2][0] += a.z * b.x; acc[2][1] += a.z * b.y; acc[2][2] += a.z * b.z; acc[2][3] += a.z * b.w;
            acc[3][0] += a.w * b.x; acc[3][1] += a.w * b.y; acc[3][2] += a.w * b.z; acc[3][3] += a.w * b.w;
        }
        __syncthreads();
    }

    float bv[4] = {0.f, 0.f, 0.f, 0.f};
    if (bias) {
        bv[0] = bias[bn + tc + 0];
        bv[1] = bias[bn + tc + 1];
        bv[2] = bias[bn + tc + 2];
        bv[3] = bias[bn + tc + 3];
    }
#pragma unroll
    for (int i = 0; i < 4; ++i) {
        int r = bm + tr + i;
        if (r < M) {
            float so = scaleOut ? scaleOut[r] : 1.f;
            float4 o;
            o.x = acc[i][0] + bv[0];
            o.y = acc[i][1] + bv[1];
            o.z = acc[i][2] + bv[2];
            o.w = acc[i][3] + bv[3];
            if (doRelu) {
                o.x = fmaxf(o.x, 0.f); o.y = fmaxf(o.y, 0.f);
                o.z = fmaxf(o.z, 0.f); o.w = fmaxf(o.w, 0.f);
            }
            o.x *= so; o.y *= so; o.z *= so; o.w *= so;
            *reinterpret_cast<float4*>(C + (size_t)r * N + bn + tc) = o;
        }
    }
}

// ---------------------------------------------------------------- chunk-parallel pooling.
// Each block covers POOL_CHUNK nodes; graph_id is sorted, so segments within a chunk are
// contiguous. Register-accumulate relu(agg2*inv_i + b2) per segment, atomicAdd at boundaries.
#define POOL_CHUNK 64
__global__ __launch_bounds__(128) void pool_kernel(const float* __restrict__ agg2,
                                                   const float* __restrict__ inv_i,
                                                   const float* __restrict__ b2,
                                                   const int* __restrict__ graph_id,
                                                   int n, float* __restrict__ hg_sum) {
    const int f = threadIdx.x;
    const int beg = blockIdx.x * POOL_CHUNK;
    const int end = min(beg + POOL_CHUNK, n);
    if (beg >= n) return;
    const float bias = b2[f];
    int g = graph_id[beg];
    float acc = 0.f;
    for (int i = beg; i < end; ++i) {
        int gi = graph_id[i];
        if (gi != g) {
            atomicAdd(&hg_sum[g * HID2 + f], acc);
            acc = 0.f;
            g = gi;
        }
        float v = agg2[(size_t)i * HID2 + f] * inv_i[i] + bias;
        acc += fmaxf(v, 0.f);
    }
    atomicAdd(&hg_sum[g * HID2 + f], acc);
}

// ---------------------------------------------------------------- tiny 3-layer MLP, block/graph
// Also divides the pooled sum by the per-graph node count (binary search on sorted graph_id).
__device__ __forceinline__ int lower_bound_i(const int* a, int n, int key) {
    int lo = 0, hi = n;
    while (lo < hi) {
        int mid = (lo + hi) >> 1;
        if (a[mid] < key) lo = mid + 1; else hi = mid;
    }
    return lo;
}

__global__ __launch_bounds__(64) void mlp_kernel(const float* __restrict__ hg_sum,
                                                 const int* __restrict__ graph_id, int n,
                                                 const float* __restrict__ Wc1, const float* __restrict__ bc1,
                                                 const float* __restrict__ Wc2, const float* __restrict__ bc2,
                                                 const float* __restrict__ Wc3, const float* __restrict__ bc3,
                                                 float* __restrict__ out) {
    const int g = blockIdx.x;
    const int t = threadIdx.x;
    __shared__ float h[HID2];
    __shared__ float t1[12];
    __shared__ float t2[12];
    __shared__ float s_inv_cnt;
    if (t == 0) {
        int beg = lower_bound_i(graph_id, n, g);
        int end = lower_bound_i(graph_id, n, g + 1);
        int c = end - beg;
        s_inv_cnt = 1.0f / (float)max(c, 1);
    }
    __syncthreads();
    const float ic = s_inv_cnt;
    for (int i = t; i < HID2; i += 64) h[i] = hg_sum[g * HID2 + i] * ic;
    __syncthreads();
    if (t < 12) {
        float a = bc1[t];
        for (int k = 0; k < HID2; ++k) a += h[k] * Wc1[k * 12 + t];
        t1[t] = a;
    }
    __syncthreads();
    if (t < 12) {
        float a = bc2[t];
        for (int k = 0; k < 12; ++k) a += t1[k] * Wc2[k * 12 + t];
        t2[t] = a;
    }
    __syncthreads();
    if (t < 10) {
        float a = bc3[t];
        for (int k = 0; k < 12; ++k) a += t2[k] * Wc3[k * 10 + t];
        out[g * 10 + t] = a;
    }
}

// ================================================================ launch
extern "C" void kernel_launch(void* const* d_in, const int* in_sizes, int n_in,
                              void* d_out, int out_size, void* d_ws, size_t ws_size,
                              hipStream_t stream) {
    const float* x        = (const float*)d_in[0];
    const int*   src      = (const int*)d_in[1];
    const int*   dst      = (const int*)d_in[2];
    const int*   graph_id = (const int*)d_in[3];
    const float* W1       = (const float*)d_in[4];
    const float* b1       = (const float*)d_in[5];
    const float* W2       = (const float*)d_in[6];
    const float* b2       = (const float*)d_in[7];
    const float* Wc1      = (const float*)d_in[8];
    const float* bc1      = (const float*)d_in[9];
    const float* Wc2      = (const float*)d_in[10];
    const float* bc2      = (const float*)d_in[11];
    const float* Wc3      = (const float*)d_in[12];
    const float* bc3      = (const float*)d_in[13];
    float* out = (float*)d_out;

    const int N = in_sizes[0] / IN_DIM;   // 50000
    const int E = in_sizes[1];            // 800000
    const int G = out_size / 10;          // 64

    char* ws = (char*)d_ws;
    size_t off = 0;
    auto alloc = [&](size_t bytes) -> char* {
        char* p = ws + off;
        off = (off + bytes + 255) & ~(size_t)255;
        return p;
    };
    int*   deg_in  = (int*)alloc((size_t)N * 4);
    int*   deg_out = (int*)alloc((size_t)N * 4);
    float* inv_i   = (float*)alloc((size_t)N * 4);
    float* inv_o   = (float*)alloc((size_t)N * 4);
    int*   row     = (int*)alloc((size_t)(N + 1) * 4);
    int*   cursor  = (int*)alloc((size_t)N * 4);
    int*   csr_src = (int*)alloc((size_t)E * 4);
    float* hg      = (float*)alloc((size_t)G * HID2 * 4);
    float* agg1    = (float*)alloc((size_t)N * IN_DIM * 4);   // reused as agg2
    float* h1      = (float*)alloc((size_t)N * HID1 * 4);
    float* xw2     = (float*)alloc((size_t)N * HID2 * 4);
    float* agg2 = agg1;

    hipMemsetAsync(deg_in, 0, (size_t)N * 4, stream);
    hipMemsetAsync(deg_out, 0, (size_t)N * 4, stream);
    hipMemsetAsync(hg, 0, (size_t)G * HID2 * 4, stream);

    hist_kernel<<<(E + 255) / 256, 256, 0, stream>>>(src, dst, deg_out, deg_in, E);
    inv_kernel<<<(N + 255) / 256, 256, 0, stream>>>(deg_in, deg_out, inv_i, inv_o, N);
    scan_kernel<<<1, 1024, 0, stream>>>(deg_in, row, cursor, N);
    scatter_kernel<<<(E + 255) / 256, 256, 0, stream>>>(src, dst, cursor, csr_src, E);

    // Layer 1, aggregate-first: agg1 = A * (x * inv_o); h1 = relu(inv_i*agg1 @ W1 + b1) * inv_o
    spmm_kernel<<<N, 128, 0, stream>>>(x, inv_o, row, csr_src, agg1);
    sgemm_kernel<<<dim3((N + TBM - 1) / TBM, HID1 / TBN), 256, 0, stream>>>(
        agg1, W1, h1, inv_i, b1, inv_o, N, HID1, IN_DIM, 1);

    // Layer 2, weight-first: xw2 = h1 @ W2 (h1 already carries inv_o); agg2 = A * xw2
    sgemm_kernel<<<dim3((N + TBM - 1) / TBM, HID2 / TBN), 256, 0, stream>>>(
        h1, W2, xw2, nullptr, nullptr, nullptr, N, HID2, HID1, 0);
    spmm_kernel<<<N, 128, 0, stream>>>(xw2, nullptr, row, csr_src, agg2);

    // Pool (fused relu(agg2*inv_i+b2), chunk-parallel) + MLP (fused mean-divide)
    pool_kernel<<<(N + POOL_CHUNK - 1) / POOL_CHUNK, 128, 0, stream>>>(agg2, inv_i, b2, graph_id, N, hg);
    mlp_kernel<<<G, 64, 0, stream>>>(hg, graph_id, N, Wc1, bc1, Wc2, bc2, Wc3, bc3, out);
}

// Round 3
// 473.311 us; speedup vs baseline: 1.6200x; 1.2129x over previous
//
#include <hip/hip_runtime.h>
#include <hip/hip_bf16.h>

#define IN_DIM 128
#define HID1 256
#define HID2 128

// ---------------------------------------------------------------- histogram
__global__ void hist_kernel(const int* __restrict__ src, const int* __restrict__ dst,
                            int* __restrict__ deg_out, int* __restrict__ deg_in, int E) {
    int e = blockIdx.x * blockDim.x + threadIdx.x;
    if (e < E) {
        atomicAdd(&deg_out[src[e]], 1);
        atomicAdd(&deg_in[dst[e]], 1);
    }
}

// ---------------------------------------------------------------- inv degree
__global__ void inv_kernel(const int* __restrict__ deg_in, const int* __restrict__ deg_out,
                           float* __restrict__ inv_i, float* __restrict__ inv_o, int n) {
    int i = blockIdx.x * blockDim.x + threadIdx.x;
    if (i < n) {
        inv_i[i] = 1.0f / sqrtf((float)max(deg_in[i], 1));
        inv_o[i] = 1.0f / sqrtf((float)max(deg_out[i], 1));
    }
}

// ---------------------------------------------------------------- 3-phase full-grid scan
#define SCAN_B 256
__global__ __launch_bounds__(SCAN_B) void scan_partial(const int* __restrict__ deg,
                                                       int* __restrict__ blockSums, int n) {
    __shared__ int sm[SCAN_B];
    int i = blockIdx.x * SCAN_B + threadIdx.x;
    int v = (i < n) ? deg[i] : 0;
    sm[threadIdx.x] = v;
    __syncthreads();
#pragma unroll
    for (int off = SCAN_B / 2; off > 0; off >>= 1) {
        if (threadIdx.x < off) sm[threadIdx.x] += sm[threadIdx.x + off];
        __syncthreads();
    }
    if (threadIdx.x == 0) blockSums[blockIdx.x] = sm[0];
}

__global__ __launch_bounds__(SCAN_B) void scan_blocksums(int* __restrict__ blockSums, int nb) {
    __shared__ int sm[SCAN_B];
    int t = threadIdx.x;
    int v = (t < nb) ? blockSums[t] : 0;
    sm[t] = v;
    __syncthreads();
#pragma unroll
    for (int off = 1; off < SCAN_B; off <<= 1) {
        int u = (t >= off) ? sm[t - off] : 0;
        __syncthreads();
        sm[t] += u;
        __syncthreads();
    }
    if (t < nb) blockSums[t] = sm[t] - v;  // exclusive
}

__global__ __launch_bounds__(SCAN_B) void scan_final(const int* __restrict__ deg,
                                                     const int* __restrict__ blockSums,
                                                     int* __restrict__ row,
                                                     int* __restrict__ cursor, int n) {
    __shared__ int sm[SCAN_B];
    int i = blockIdx.x * SCAN_B + threadIdx.x;
    int v = (i < n) ? deg[i] : 0;
    sm[threadIdx.x] = v;
    __syncthreads();
#pragma unroll
    for (int off = 1; off < SCAN_B; off <<= 1) {
        int u = (threadIdx.x >= off) ? sm[threadIdx.x - off] : 0;
        __syncthreads();
        sm[threadIdx.x] += u;
        __syncthreads();
    }
    int excl = sm[threadIdx.x] - v + blockSums[blockIdx.x];
    if (i < n) {
        row[i] = excl;
        cursor[i] = excl;
        if (i == n - 1) row[n] = excl + v;
    }
}

// ---------------------------------------------------------------- scatter into CSR
__global__ void scatter_kernel(const int* __restrict__ src, const int* __restrict__ dst,
                               int* __restrict__ cursor, int* __restrict__ csr_src, int E) {
    int e = blockIdx.x * blockDim.x + threadIdx.x;
    if (e < E) {
        int p = atomicAdd(&cursor[dst[e]], 1);
        csr_src[p] = src[e];
    }
}

// ---------------------------------------------------------------- node-parallel CSR SpMM (F=128)
// out[i][f] = sum_{j in row[i]..row[i+1]} feat[csr_src[j]][f] * (scale ? scale[csr_src[j]] : 1)
__global__ __launch_bounds__(128) void spmm_kernel(const float* __restrict__ feat,
                                                   const float* __restrict__ scale,
                                                   const int* __restrict__ row,
                                                   const int* __restrict__ csr_src,
                                                   float* __restrict__ out) {
    const int i = blockIdx.x;
    const int f = threadIdx.x;
    const int beg = row[i];
    const int end = row[i + 1];
    float acc = 0.f;
    int j = beg;
    if (scale) {
        for (; j + 4 <= end; j += 4) {
            int s0 = csr_src[j], s1 = csr_src[j + 1], s2 = csr_src[j + 2], s3 = csr_src[j + 3];
            float c0 = scale[s0], c1 = scale[s1], c2 = scale[s2], c3 = scale[s3];
            acc += feat[(size_t)s0 * IN_DIM + f] * c0;
            acc += feat[(size_t)s1 * IN_DIM + f] * c1;
            acc += feat[(size_t)s2 * IN_DIM + f] * c2;
            acc += feat[(size_t)s3 * IN_DIM + f] * c3;
        }
        for (; j < end; ++j) {
            int s0 = csr_src[j];
            acc += feat[(size_t)s0 * IN_DIM + f] * scale[s0];
        }
    } else {
        for (; j + 4 <= end; j += 4) {
            int s0 = csr_src[j], s1 = csr_src[j + 1], s2 = csr_src[j + 2], s3 = csr_src[j + 3];
            acc += feat[(size_t)s0 * IN_DIM + f];
            acc += feat[(size_t)s1 * IN_DIM + f];
            acc += feat[(size_t)s2 * IN_DIM + f];
            acc += feat[(size_t)s3 * IN_DIM + f];
        }
        for (; j < end; ++j) acc += feat[(size_t)csr_src[j] * IN_DIM + f];
    }
    out[(size_t)i * IN_DIM + f] = acc;
}

// ---------------------------------------------------------------- tiled fp32 GEMM with fused
// row-scale on A, bias, relu, row-scale on output.
// C[r][c] = ((sum_k A[r][k]*scaleA[r]*B[k][c]) + bias[c]) -> relu? -> * scaleOut[r]
#define TBM 64
#define TBN 64
#define TBK 32
__global__ __launch_bounds__(256) void sgemm_kernel(const float* __restrict__ A,
                                                    const float* __restrict__ B,
                                                    float* __restrict__ C,
                                                    const float* __restrict__ scaleA,
                                                    const float* __restrict__ bias,
                                                    const float* __restrict__ scaleOut,
                                                    int M, int N, int K, int doRelu) {
    __shared__ float As[TBK][TBM + 4];  // +4 keeps 16B alignment, breaks bank stride
    __shared__ float Bs[TBK][TBN];
    const int tid = threadIdx.x;
    const int bm = blockIdx.x * TBM;
    const int bn = blockIdx.y * TBN;
    const int tr = (tid >> 4) << 2;  // row offset in tile, 0..60
    const int tc = (tid & 15) << 2;  // col offset in tile, 0..60
    float acc[4][4] = {};

    for (int k0 = 0; k0 < K; k0 += TBK) {
        // load A tile 64x32 (transposed into LDS), 2 float4 per thread
#pragma unroll
        for (int i = 0; i < 2; ++i) {
            int slot = tid + (i << 8);
            int r = slot >> 3;
            int c = (slot & 7) << 2;
            int grow = bm + r;
            float4 v = make_float4(0.f, 0.f, 0.f, 0.f);
            if (grow < M) {
                v = *reinterpret_cast<const float4*>(A + (size_t)grow * K + k0 + c);
                if (scaleA) {
                    float s = scaleA[grow];
                    v.x *= s; v.y *= s; v.z *= s; v.w *= s;
                }
            }
            As[c + 0][r] = v.x;
            As[c + 1][r] = v.y;
            As[c + 2][r] = v.z;
            As[c + 3][r] = v.w;
        }
        // load B tile 32x64, 2 float4 per thread
#pragma unroll
        for (int i = 0; i < 2; ++i) {
            int slot = tid + (i << 8);
            int r = slot >> 4;
            int c = (slot & 15) << 2;
            float4 v = *reinterpret_cast<const float4*>(B + (size_t)(k0 + r) * N + bn + c);
            *reinterpret_cast<float4*>(&Bs[r][c]) = v;
        }
        __syncthreads();
#pragma unroll
        for (int kk = 0; kk < TBK; ++kk) {
            float4 a = *reinterpret_cast<const float4*>(&As[kk][tr]);
            float4 b = *reinterpret_cast<const float4*>(&Bs[kk][tc]);
            acc[0][0] += a.x * b.x; acc[0][1] += a.x * b.y; acc[0][2] += a.x * b.z; acc[0][3] += a.x * b.w;
            acc[1][0] += a.y * b.x; acc[1][1] += a.y * b.y; acc[1][2] += a.y * b.z; acc[1][3] += a.y * b.w;
            acc[2][0] += a.z * b.x; acc[2][1] += a.z * b.y; acc[2][2] += a.z * b.z; acc[2][3] += a.z * b.w;
            acc[3][0] += a.w * b.x; acc[3][1] += a.w * b.y; acc[3][2] += a.w * b.z; acc[3][3] += a.w * b.w;
        }
        __syncthreads();
    }

    float bv[4] = {0.f, 0.f, 0.f, 0.f};
    if (bias) {
        bv[0] = bias[bn + tc + 0];
        bv[1] = bias[bn + tc + 1];
        bv[2] = bias[bn + tc + 2];
        bv[3] = bias[bn + tc + 3];
    }
#pragma unroll
    for (int i = 0; i < 4; ++i) {
        int r = bm + tr + i;
        if (r < M) {
            float so = scaleOut ? scaleOut[r] : 1.f;
            float4 o;
            o.x = acc[i][0] + bv[0];
            o.y = acc[i][1] + bv[1];
            o.z = acc[i][2] + bv[2];
            o.w = acc[i][3] + bv[3];
            if (doRelu) {
                o.x = fmaxf(o.x, 0.f); o.y = fmaxf(o.y, 0.f);
                o.z = fmaxf(o.z, 0.f); o.w = fmaxf(o.w, 0.f);
            }
            o.x *= so; o.y *= so; o.z *= so; o.w *= so;
            *reinterpret_cast<float4*>(C + (size_t)r * N + bn + tc) = o;
        }
    }
}

// ---------------------------------------------------------------- chunk-parallel pooling.
#define POOL_CHUNK 64
__global__ __launch_bounds__(128) void pool_kernel(const float* __restrict__ agg2,
                                                   const float* __restrict__ inv_i,
                                                   const float* __restrict__ b2,
                                                   const int* __restrict__ graph_id,
                                                   int n, float* __restrict__ hg_sum) {
    const int f = threadIdx.x;
    const int beg = blockIdx.x * POOL_CHUNK;
    const int end = min(beg + POOL_CHUNK, n);
    if (beg >= n) return;
    const float bias = b2[f];
    int g = graph_id[beg];
    float acc = 0.f;
    for (int i = beg; i < end; ++i) {
        int gi = graph_id[i];
        if (gi != g) {
            atomicAdd(&hg_sum[g * HID2 + f], acc);
            acc = 0.f;
            g = gi;
        }
        float v = agg2[(size_t)i * HID2 + f] * inv_i[i] + bias;
        acc += fmaxf(v, 0.f);
    }
    atomicAdd(&hg_sum[g * HID2 + f], acc);
}

// ---------------------------------------------------------------- tiny 3-layer MLP, block/graph
__device__ __forceinline__ int lower_bound_i(const int* a, int n, int key) {
    int lo = 0, hi = n;
    while (lo < hi) {
        int mid = (lo + hi) >> 1;
        if (a[mid] < key) lo = mid + 1; else hi = mid;
    }
    return lo;
}

__global__ __launch_bounds__(64) void mlp_kernel(const float* __restrict__ hg_sum,
                                                 const int* __restrict__ graph_id, int n,
                                                 const float* __restrict__ Wc1, const float* __restrict__ bc1,
                                                 const float* __restrict__ Wc2, const float* __restrict__ bc2,
                                                 const float* __restrict__ Wc3, const float* __restrict__ bc3,
                                                 float* __restrict__ out) {
    const int g = blockIdx.x;
    const int t = threadIdx.x;
    __shared__ float h[HID2];
    __shared__ float t1[12];
    __shared__ float t2[12];
    __shared__ float s_inv_cnt;
    if (t == 0) {
        int beg = lower_bound_i(graph_id, n, g);
        int end = lower_bound_i(graph_id, n, g + 1);
        int c = end - beg;
        s_inv_cnt = 1.0f / (float)max(c, 1);
    }
    __syncthreads();
    const float ic = s_inv_cnt;
    for (int i = t; i < HID2; i += 64) h[i] = hg_sum[g * HID2 + i] * ic;
    __syncthreads();
    if (t < 12) {
        float a = bc1[t];
        for (int k = 0; k < HID2; ++k) a += h[k] * Wc1[k * 12 + t];
        t1[t] = a;
    }
    __syncthreads();
    if (t < 12) {
        float a = bc2[t];
        for (int k = 0; k < 12; ++k) a += t1[k] * Wc2[k * 12 + t];
        t2[t] = a;
    }
    __syncthreads();
    if (t < 10) {
        float a = bc3[t];
        for (int k = 0; k < 12; ++k) a += t2[k] * Wc3[k * 10 + t];
        out[g * 10 + t] = a;
    }
}

// ================================================================ launch
extern "C" void kernel_launch(void* const* d_in, const int* in_sizes, int n_in,
                              void* d_out, int out_size, void* d_ws, size_t ws_size,
                              hipStream_t stream) {
    const float* x        = (const float*)d_in[0];
    const int*   src      = (const int*)d_in[1];
    const int*   dst      = (const int*)d_in[2];
    const int*   graph_id = (const int*)d_in[3];
    const float* W1       = (const float*)d_in[4];
    const float* b1       = (const float*)d_in[5];
    const float* W2       = (const float*)d_in[6];
    const float* b2       = (const float*)d_in[7];
    const float* Wc1      = (const float*)d_in[8];
    const float* bc1      = (const float*)d_in[9];
    const float* Wc2      = (const float*)d_in[10];
    const float* bc2      = (const float*)d_in[11];
    const float* Wc3      = (const float*)d_in[12];
    const float* bc3      = (const float*)d_in[13];
    float* out = (float*)d_out;

    const int N = in_sizes[0] / IN_DIM;   // 50000
    const int E = in_sizes[1];            // 800000
    const int G = out_size / 10;          // 64

    char* ws = (char*)d_ws;
    size_t off = 0;
    auto alloc = [&](size_t bytes) -> char* {
        char* p = ws + off;
        off = (off + bytes + 255) & ~(size_t)255;
        return p;
    };
    const int NB = (N + SCAN_B - 1) / SCAN_B;   // 196 scan blocks
    int*   deg_in  = (int*)alloc((size_t)N * 4);
    int*   deg_out = (int*)alloc((size_t)N * 4);
    float* inv_i   = (float*)alloc((size_t)N * 4);
    float* inv_o   = (float*)alloc((size_t)N * 4);
    int*   row     = (int*)alloc((size_t)(N + 1) * 4);
    int*   cursor  = (int*)alloc((size_t)N * 4);
    int*   bsums   = (int*)alloc((size_t)NB * 4);
    int*   csr_src = (int*)alloc((size_t)E * 4);
    float* hg      = (float*)alloc((size_t)G * HID2 * 4);
    float* agg1    = (float*)alloc((size_t)N * IN_DIM * 4);   // reused as agg2
    float* h1      = (float*)alloc((size_t)N * HID1 * 4);
    float* xw2     = (float*)alloc((size_t)N * HID2 * 4);
    float* agg2 = agg1;

    hipMemsetAsync(deg_in, 0, (size_t)N * 4, stream);
    hipMemsetAsync(deg_out, 0, (size_t)N * 4, stream);
    hipMemsetAsync(hg, 0, (size_t)G * HID2 * 4, stream);

    hist_kernel<<<(E + 255) / 256, 256, 0, stream>>>(src, dst, deg_out, deg_in, E);
    inv_kernel<<<(N + 255) / 256, 256, 0, stream>>>(deg_in, deg_out, inv_i, inv_o, N);
    scan_partial<<<NB, SCAN_B, 0, stream>>>(deg_in, bsums, N);
    scan_blocksums<<<1, SCAN_B, 0, stream>>>(bsums, NB);
    scan_final<<<NB, SCAN_B, 0, stream>>>(deg_in, bsums, row, cursor, N);
    scatter_kernel<<<(E + 255) / 256, 256, 0, stream>>>(src, dst, cursor, csr_src, E);

    // Layer 1, aggregate-first: agg1 = A * (x * inv_o); h1 = relu(inv_i*agg1 @ W1 + b1) * inv_o
    spmm_kernel<<<N, 128, 0, stream>>>(x, inv_o, row, csr_src, agg1);
    sgemm_kernel<<<dim3((N + TBM - 1) / TBM, HID1 / TBN), 256, 0, stream>>>(
        agg1, W1, h1, inv_i, b1, inv_o, N, HID1, IN_DIM, 1);

    // Layer 2, weight-first: xw2 = h1 @ W2 (h1 already carries inv_o); agg2 = A * xw2
    sgemm_kernel<<<dim3((N + TBM - 1) / TBM, HID2 / TBN), 256, 0, stream>>>(
        h1, W2, xw2, nullptr, nullptr, nullptr, N, HID2, HID1, 0);
    spmm_kernel<<<N, 128, 0, stream>>>(xw2, nullptr, row, csr_src, agg2);

    // Pool (fused relu(agg2*inv_i+b2), chunk-parallel) + MLP (fused mean-divide)
    pool_kernel<<<(N + POOL_CHUNK - 1) / POOL_CHUNK, 128, 0, stream>>>(agg2, inv_i, b2, graph_id, N, hg);
    mlp_kernel<<<G, 64, 0, stream>>>(hg, graph_id, N, Wc1, bc1, Wc2, bc2, Wc3, bc3, out);
}

// Round 4
// 385.061 us; speedup vs baseline: 1.9913x; 1.2292x over previous
//
#include <hip/hip_runtime.h>
#include <hip/hip_bf16.h>

#define IN_DIM 128
#define HID1 256
#define HID2 128

// ---------------------------------------------------------------- histogram
__global__ void hist_kernel(const int* __restrict__ src, const int* __restrict__ dst,
                            int* __restrict__ deg_out, int* __restrict__ deg_in, int E) {
    int e = blockIdx.x * blockDim.x + threadIdx.x;
    if (e < E) {
        atomicAdd(&deg_out[src[e]], 1);
        atomicAdd(&deg_in[dst[e]], 1);
    }
}

// ---------------------------------------------------------------- inv degree
__global__ void inv_kernel(const int* __restrict__ deg_in, const int* __restrict__ deg_out,
                           float* __restrict__ inv_i, float* __restrict__ inv_o, int n) {
    int i = blockIdx.x * blockDim.x + threadIdx.x;
    if (i < n) {
        inv_i[i] = 1.0f / sqrtf((float)max(deg_in[i], 1));
        inv_o[i] = 1.0f / sqrtf((float)max(deg_out[i], 1));
    }
}

// ---------------------------------------------------------------- 3-phase full-grid scan
#define SCAN_B 256
__global__ __launch_bounds__(SCAN_B) void scan_partial(const int* __restrict__ deg,
                                                       int* __restrict__ blockSums, int n) {
    __shared__ int sm[SCAN_B];
    int i = blockIdx.x * SCAN_B + threadIdx.x;
    int v = (i < n) ? deg[i] : 0;
    sm[threadIdx.x] = v;
    __syncthreads();
#pragma unroll
    for (int off = SCAN_B / 2; off > 0; off >>= 1) {
        if (threadIdx.x < off) sm[threadIdx.x] += sm[threadIdx.x + off];
        __syncthreads();
    }
    if (threadIdx.x == 0) blockSums[blockIdx.x] = sm[0];
}

__global__ __launch_bounds__(SCAN_B) void scan_blocksums(int* __restrict__ blockSums, int nb) {
    __shared__ int sm[SCAN_B];
    int t = threadIdx.x;
    int v = (t < nb) ? blockSums[t] : 0;
    sm[t] = v;
    __syncthreads();
#pragma unroll
    for (int off = 1; off < SCAN_B; off <<= 1) {
        int u = (t >= off) ? sm[t - off] : 0;
        __syncthreads();
        sm[t] += u;
        __syncthreads();
    }
    if (t < nb) blockSums[t] = sm[t] - v;  // exclusive
}

__global__ __launch_bounds__(SCAN_B) void scan_final(const int* __restrict__ deg,
                                                     const int* __restrict__ blockSums,
                                                     int* __restrict__ row,
                                                     int* __restrict__ cursor, int n) {
    __shared__ int sm[SCAN_B];
    int i = blockIdx.x * SCAN_B + threadIdx.x;
    int v = (i < n) ? deg[i] : 0;
    sm[threadIdx.x] = v;
    __syncthreads();
#pragma unroll
    for (int off = 1; off < SCAN_B; off <<= 1) {
        int u = (threadIdx.x >= off) ? sm[threadIdx.x - off] : 0;
        __syncthreads();
        sm[threadIdx.x] += u;
        __syncthreads();
    }
    int excl = sm[threadIdx.x] - v + blockSums[blockIdx.x];
    if (i < n) {
        row[i] = excl;
        cursor[i] = excl;
        if (i == n - 1) row[n] = excl + v;
    }
}

// ---------------------------------------------------------------- scatter into CSR
__global__ void scatter_kernel(const int* __restrict__ src, const int* __restrict__ dst,
                               int* __restrict__ cursor, int* __restrict__ csr_src, int E) {
    int e = blockIdx.x * blockDim.x + threadIdx.x;
    if (e < E) {
        int p = atomicAdd(&cursor[dst[e]], 1);
        csr_src[p] = src[e];
    }
}

// ---------------------------------------------------------------- fp32 -> bf16 bulk convert
__global__ void cvt_kernel(const float* __restrict__ in, __hip_bfloat16* __restrict__ out, int n4) {
    int i = blockIdx.x * blockDim.x + threadIdx.x;
    if (i < n4) {
        float4 v = reinterpret_cast<const float4*>(in)[i];
        __hip_bfloat16 b0 = __float2bfloat16(v.x);
        __hip_bfloat16 b1 = __float2bfloat16(v.y);
        __hip_bfloat16 b2 = __float2bfloat16(v.z);
        __hip_bfloat16 b3 = __float2bfloat16(v.w);
        ushort4 o = make_ushort4(*(unsigned short*)&b0, *(unsigned short*)&b1,
                                 *(unsigned short*)&b2, *(unsigned short*)&b3);
        reinterpret_cast<ushort4*>(out)[i] = o;
    }
}

// ---------------------------------------------------------------- fp32 [K][N] -> bf16 [N][K]
__global__ void cvt_transpose_kernel(const float* __restrict__ W, __hip_bfloat16* __restrict__ Wt,
                                     int K, int N) {
    int idx = blockIdx.x * blockDim.x + threadIdx.x;
    if (idx < K * N) {
        int k = idx / N;
        int n = idx - k * N;
        Wt[n * K + k] = __float2bfloat16(W[idx]);
    }
}

// ---------------------------------------------------------------- node-parallel CSR SpMM, bf16
// feat, F=128. acc fp32; out either bf16 or fp32.
__global__ __launch_bounds__(128) void spmm_kernel(const __hip_bfloat16* __restrict__ feat,
                                                   const float* __restrict__ scale,
                                                   const int* __restrict__ row,
                                                   const int* __restrict__ csr_src,
                                                   __hip_bfloat16* __restrict__ out_bf,
                                                   float* __restrict__ out_f32) {
    const int i = blockIdx.x;
    const int f = threadIdx.x;
    const int beg = row[i];
    const int end = row[i + 1];
    float acc = 0.f;
    int j = beg;
    if (scale) {
        for (; j + 4 <= end; j += 4) {
            int s0 = csr_src[j], s1 = csr_src[j + 1], s2 = csr_src[j + 2], s3 = csr_src[j + 3];
            float c0 = scale[s0], c1 = scale[s1], c2 = scale[s2], c3 = scale[s3];
            acc += __bfloat162float(feat[(size_t)s0 * IN_DIM + f]) * c0;
            acc += __bfloat162float(feat[(size_t)s1 * IN_DIM + f]) * c1;
            acc += __bfloat162float(feat[(size_t)s2 * IN_DIM + f]) * c2;
            acc += __bfloat162float(feat[(size_t)s3 * IN_DIM + f]) * c3;
        }
        for (; j < end; ++j) {
            int s0 = csr_src[j];
            acc += __bfloat162float(feat[(size_t)s0 * IN_DIM + f]) * scale[s0];
        }
    } else {
        for (; j + 4 <= end; j += 4) {
            int s0 = csr_src[j], s1 = csr_src[j + 1], s2 = csr_src[j + 2], s3 = csr_src[j + 3];
            acc += __bfloat162float(feat[(size_t)s0 * IN_DIM + f]);
            acc += __bfloat162float(feat[(size_t)s1 * IN_DIM + f]);
            acc += __bfloat162float(feat[(size_t)s2 * IN_DIM + f]);
            acc += __bfloat162float(feat[(size_t)s3 * IN_DIM + f]);
        }
        for (; j < end; ++j) acc += __bfloat162float(feat[(size_t)csr_src[j] * IN_DIM + f]);
    }
    if (out_bf) out_bf[(size_t)i * IN_DIM + f] = __float2bfloat16(acc);
    else        out_f32[(size_t)i * IN_DIM + f] = acc;
}

// ---------------------------------------------------------------- MFMA bf16 GEMM
// C[r][c] = epilogue( sum_k A[r][k] * Bt[c][k] )
// epilogue: *scaleR[r] (opt) + bias[c] (opt) -> relu (opt) -> *scaleO[r] (opt) -> bf16
// Tiles: block 128x128, BK=32; 4 waves 2x2, each wave 64x64 = 4x4 MFMA 16x16x32 frags.
// LDS rows padded to 40 bf16 (80 B): lanes alias banks 2-way max (free).
#define GBM 128
#define GBN 128
#define GBK 32
#define LPAD 40
typedef __attribute__((ext_vector_type(4))) float floatx4;
typedef __attribute__((ext_vector_type(8))) short shortx8;

__global__ __launch_bounds__(256) void mfma_gemm_kernel(const __hip_bfloat16* __restrict__ A,
                                                        const __hip_bfloat16* __restrict__ Bt,
                                                        __hip_bfloat16* __restrict__ C,
                                                        const float* __restrict__ scaleR,
                                                        const float* __restrict__ bias,
                                                        const float* __restrict__ scaleO,
                                                        int M, int Nn, int K, int doRelu) {
    __shared__ __align__(16) __hip_bfloat16 As[GBM * LPAD];
    __shared__ __align__(16) __hip_bfloat16 Bs[GBN * LPAD];
    const int tid = threadIdx.x;
    const int bm = blockIdx.x * GBM;
    const int bn = blockIdx.y * GBN;
    const int wid = tid >> 6;
    const int lane = tid & 63;
    const int wm = (wid & 1) * 64;
    const int wn = (wid >> 1) * 64;
    const int lrow = lane & 15;
    const int quad = lane >> 4;

    floatx4 acc[4][4] = {};

    for (int k0 = 0; k0 < K; k0 += GBK) {
        // stage A tile: 128 rows x 32 k, 8 bf16 (16B) per thread x 2
#pragma unroll
        for (int it = 0; it < 2; ++it) {
            int slot = tid + (it << 8);           // 0..511
            int r = slot >> 2;                    // 0..127
            int c = (slot & 3) << 3;              // 0,8,16,24
            int gr = bm + r;
            float4 v = make_float4(0.f, 0.f, 0.f, 0.f);
            if (gr < M) v = *reinterpret_cast<const float4*>(A + (size_t)gr * K + k0 + c);
            *reinterpret_cast<float4*>(&As[r * LPAD + c]) = v;
        }
        // stage Bt tile: 128 n-rows x 32 k (Nn is always a multiple of 128 here)
#pragma unroll
        for (int it = 0; it < 2; ++it) {
            int slot = tid + (it << 8);
            int r = slot >> 2;
            int c = (slot & 3) << 3;
            float4 v = *reinterpret_cast<const float4*>(Bt + (size_t)(bn + r) * K + k0 + c);
            *reinterpret_cast<float4*>(&Bs[r * LPAD + c]) = v;
        }
        __syncthreads();

        shortx8 af[4], bf[4];
#pragma unroll
        for (int i = 0; i < 4; ++i)
            af[i] = *reinterpret_cast<const shortx8*>(&As[(wm + i * 16 + lrow) * LPAD + quad * 8]);
#pragma unroll
        for (int i = 0; i < 4; ++i)
            bf[i] = *reinterpret_cast<const shortx8*>(&Bs[(wn + i * 16 + lrow) * LPAD + quad * 8]);
#pragma unroll
        for (int im = 0; im < 4; ++im)
#pragma unroll
            for (int in = 0; in < 4; ++in)
                acc[im][in] = __builtin_amdgcn_mfma_f32_16x16x32_bf16(af[im], bf[in], acc[im][in], 0, 0, 0);
        __syncthreads();
    }

    // bias per column (depends on `in` only)
    float bv[4];
#pragma unroll
    for (int in = 0; in < 4; ++in)
        bv[in] = bias ? bias[bn + wn + in * 16 + lrow] : 0.f;

    // C/D layout: row = quad*4 + reg, col = lrow (per 16x16 tile)
#pragma unroll
    for (int im = 0; im < 4; ++im) {
#pragma unroll
        for (int reg = 0; reg < 4; ++reg) {
            int r = bm + wm + im * 16 + quad * 4 + reg;
            if (r >= M) continue;
            float sR = scaleR ? scaleR[r] : 1.f;
            float sO = scaleO ? scaleO[r] : 1.f;
#pragma unroll
            for (int in = 0; in < 4; ++in) {
                int c = bn + wn + in * 16 + lrow;
                float v = acc[im][in][reg] * sR + bv[in];
                if (doRelu) v = fmaxf(v, 0.f);
                v *= sO;
                C[(size_t)r * Nn + c] = __float2bfloat16(v);
            }
        }
    }
}

// ---------------------------------------------------------------- chunk-parallel pooling.
#define POOL_CHUNK 64
__global__ __launch_bounds__(128) void pool_kernel(const float* __restrict__ agg2,
                                                   const float* __restrict__ inv_i,
                                                   const float* __restrict__ b2,
                                                   const int* __restrict__ graph_id,
                                                   int n, float* __restrict__ hg_sum) {
    const int f = threadIdx.x;
    const int beg = blockIdx.x * POOL_CHUNK;
    const int end = min(beg + POOL_CHUNK, n);
    if (beg >= n) return;
    const float bias = b2[f];
    int g = graph_id[beg];
    float acc = 0.f;
    for (int i = beg; i < end; ++i) {
        int gi = graph_id[i];
        if (gi != g) {
            atomicAdd(&hg_sum[g * HID2 + f], acc);
            acc = 0.f;
            g = gi;
        }
        float v = agg2[(size_t)i * HID2 + f] * inv_i[i] + bias;
        acc += fmaxf(v, 0.f);
    }
    atomicAdd(&hg_sum[g * HID2 + f], acc);
}

// ---------------------------------------------------------------- tiny 3-layer MLP, block/graph
__device__ __forceinline__ int lower_bound_i(const int* a, int n, int key) {
    int lo = 0, hi = n;
    while (lo < hi) {
        int mid = (lo + hi) >> 1;
        if (a[mid] < key) lo = mid + 1; else hi = mid;
    }
    return lo;
}

__global__ __launch_bounds__(64) void mlp_kernel(const float* __restrict__ hg_sum,
                                                 const int* __restrict__ graph_id, int n,
                                                 const float* __restrict__ Wc1, const float* __restrict__ bc1,
                                                 const float* __restrict__ Wc2, const float* __restrict__ bc2,
                                                 const float* __restrict__ Wc3, const float* __restrict__ bc3,
                                                 float* __restrict__ out) {
    const int g = blockIdx.x;
    const int t = threadIdx.x;
    __shared__ float h[HID2];
    __shared__ float t1[12];
    __shared__ float t2[12];
    __shared__ float s_inv_cnt;
    if (t == 0) {
        int beg = lower_bound_i(graph_id, n, g);
        int end = lower_bound_i(graph_id, n, g + 1);
        int c = end - beg;
        s_inv_cnt = 1.0f / (float)max(c, 1);
    }
    __syncthreads();
    const float ic = s_inv_cnt;
    for (int i = t; i < HID2; i += 64) h[i] = hg_sum[g * HID2 + i] * ic;
    __syncthreads();
    if (t < 12) {
        float a = bc1[t];
        for (int k = 0; k < HID2; ++k) a += h[k] * Wc1[k * 12 + t];
        t1[t] = a;
    }
    __syncthreads();
    if (t < 12) {
        float a = bc2[t];
        for (int k = 0; k < 12; ++k) a += t1[k] * Wc2[k * 12 + t];
        t2[t] = a;
    }
    __syncthreads();
    if (t < 10) {
        float a = bc3[t];
        for (int k = 0; k < 12; ++k) a += t2[k] * Wc3[k * 10 + t];
        out[g * 10 + t] = a;
    }
}

// ================================================================ launch
extern "C" void kernel_launch(void* const* d_in, const int* in_sizes, int n_in,
                              void* d_out, int out_size, void* d_ws, size_t ws_size,
                              hipStream_t stream) {
    const float* x        = (const float*)d_in[0];
    const int*   src      = (const int*)d_in[1];
    const int*   dst      = (const int*)d_in[2];
    const int*   graph_id = (const int*)d_in[3];
    const float* W1       = (const float*)d_in[4];
    const float* b1       = (const float*)d_in[5];
    const float* W2       = (const float*)d_in[6];
    const float* b2       = (const float*)d_in[7];
    const float* Wc1      = (const float*)d_in[8];
    const float* bc1      = (const float*)d_in[9];
    const float* Wc2      = (const float*)d_in[10];
    const float* bc2      = (const float*)d_in[11];
    const float* Wc3      = (const float*)d_in[12];
    const float* bc3      = (const float*)d_in[13];
    float* out = (float*)d_out;

    const int N = in_sizes[0] / IN_DIM;   // 50000
    const int E = in_sizes[1];            // 800000
    const int G = out_size / 10;          // 64

    char* ws = (char*)d_ws;
    size_t off = 0;
    auto alloc = [&](size_t bytes) -> char* {
        char* p = ws + off;
        off = (off + bytes + 255) & ~(size_t)255;
        return p;
    };
    const int NB = (N + SCAN_B - 1) / SCAN_B;
    int*   deg_in  = (int*)alloc((size_t)N * 4);
    int*   deg_out = (int*)alloc((size_t)N * 4);
    float* inv_i   = (float*)alloc((size_t)N * 4);
    float* inv_o   = (float*)alloc((size_t)N * 4);
    int*   row     = (int*)alloc((size_t)(N + 1) * 4);
    int*   cursor  = (int*)alloc((size_t)N * 4);
    int*   bsums   = (int*)alloc((size_t)NB * 4);
    int*   csr_src = (int*)alloc((size_t)E * 4);
    float* hg      = (float*)alloc((size_t)G * HID2 * 4);
    __hip_bfloat16* x_bf    = (__hip_bfloat16*)alloc((size_t)N * IN_DIM * 2);
    __hip_bfloat16* W1t     = (__hip_bfloat16*)alloc((size_t)IN_DIM * HID1 * 2);
    __hip_bfloat16* W2t     = (__hip_bfloat16*)alloc((size_t)HID1 * HID2 * 2);
    __hip_bfloat16* agg1_bf = (__hip_bfloat16*)alloc((size_t)N * IN_DIM * 2);
    __hip_bfloat16* h1_bf   = (__hip_bfloat16*)alloc((size_t)N * HID1 * 2);
    __hip_bfloat16* xw2_bf  = (__hip_bfloat16*)alloc((size_t)N * HID2 * 2);
    float* agg2    = (float*)alloc((size_t)N * HID2 * 4);

    hipMemsetAsync(deg_in, 0, (size_t)N * 4, stream);
    hipMemsetAsync(deg_out, 0, (size_t)N * 4, stream);
    hipMemsetAsync(hg, 0, (size_t)G * HID2 * 4, stream);

    // graph structure
    hist_kernel<<<(E + 255) / 256, 256, 0, stream>>>(src, dst, deg_out, deg_in, E);
    inv_kernel<<<(N + 255) / 256, 256, 0, stream>>>(deg_in, deg_out, inv_i, inv_o, N);
    scan_partial<<<NB, SCAN_B, 0, stream>>>(deg_in, bsums, N);
    scan_blocksums<<<1, SCAN_B, 0, stream>>>(bsums, NB);
    scan_final<<<NB, SCAN_B, 0, stream>>>(deg_in, bsums, row, cursor, N);
    scatter_kernel<<<(E + 255) / 256, 256, 0, stream>>>(src, dst, cursor, csr_src, E);

    // bf16 conversions
    cvt_kernel<<<(N * IN_DIM / 4 + 255) / 256, 256, 0, stream>>>(x, x_bf, N * IN_DIM / 4);
    cvt_transpose_kernel<<<(IN_DIM * HID1 + 255) / 256, 256, 0, stream>>>(W1, W1t, IN_DIM, HID1);
    cvt_transpose_kernel<<<(HID1 * HID2 + 255) / 256, 256, 0, stream>>>(W2, W2t, HID1, HID2);

    // Layer 1, aggregate-first: agg1 = A * (x * inv_o); h1 = relu(inv_i*(agg1@W1) + b1) * inv_o
    spmm_kernel<<<N, 128, 0, stream>>>(x_bf, inv_o, row, csr_src, agg1_bf, nullptr);
    mfma_gemm_kernel<<<dim3((N + GBM - 1) / GBM, HID1 / GBN), 256, 0, stream>>>(
        agg1_bf, W1t, h1_bf, inv_i, b1, inv_o, N, HID1, IN_DIM, 1);

    // Layer 2, weight-first: xw2 = h1 @ W2 (h1 carries inv_o); agg2 = A * xw2
    mfma_gemm_kernel<<<dim3((N + GBM - 1) / GBM, HID2 / GBN), 256, 0, stream>>>(
        h1_bf, W2t, xw2_bf, nullptr, nullptr, nullptr, N, HID2, HID1, 0);
    spmm_kernel<<<N, 128, 0, stream>>>(xw2_bf, nullptr, row, csr_src, nullptr, agg2);

    // Pool (fused relu(agg2*inv_i+b2), chunk-parallel) + MLP (fused mean-divide)
    pool_kernel<<<(N + POOL_CHUNK - 1) / POOL_CHUNK, 128, 0, stream>>>(agg2, inv_i, b2, graph_id, N, hg);
    mlp_kernel<<<G, 64, 0, stream>>>(hg, graph_id, N, Wc1, bc1, Wc2, bc2, Wc3, bc3, out);
}

// Round 5
// 319.471 us; speedup vs baseline: 2.4001x; 1.2053x over previous
//
#include <hip/hip_runtime.h>
#include <hip/hip_bf16.h>

#define IN_DIM 128
#define HID1 256
#define HID2 128

// ---------------------------------------------------------------- privatized histogram
// Grid: (n_chunks, n_ranges, 2[z=0:dst->in, z=1:src->out]).
// Each block counts its edge chunk for its bin range into LDS (two 16-bit counters
// packed per 32-bit word; chunk_size <= 65535 so no overflow), then dumps unpacked
// per-chunk partials. No global atomics.
#define HB_BINS 25000
#define HB_WORDS 12500
#define HB_CHUNKS 64
__global__ __launch_bounds__(256) void hist_count(const int* __restrict__ src,
                                                  const int* __restrict__ dst,
                                                  int E, int chunk_size,
                                                  int* __restrict__ part_in,
                                                  int* __restrict__ part_out, int N) {
    __shared__ int sm[HB_WORDS];
    const int* idx = (blockIdx.z == 0) ? dst : src;
    int* part = (blockIdx.z == 0) ? part_in : part_out;
    const int base = blockIdx.y * HB_BINS;
    const int ebeg = blockIdx.x * chunk_size;
    const int eend = min(ebeg + chunk_size, E);
    for (int w = threadIdx.x; w < HB_WORDS; w += 256) sm[w] = 0;
    __syncthreads();
    for (int e = ebeg + threadIdx.x; e < eend; e += 256) {
        int v = idx[e] - base;
        if ((unsigned)v < (unsigned)HB_BINS)
            atomicAdd(&sm[v >> 1], 1 << ((v & 1) * 16));
    }
    __syncthreads();
    const int nb = min(HB_BINS, N - base);
    int* dp = part + (size_t)blockIdx.x * N + base;
    for (int w = threadIdx.x; 2 * w < nb; w += 256) {
        int packed = sm[w];
        int b = 2 * w;
        dp[b] = packed & 0xffff;
        if (b + 1 < nb) dp[b + 1] = (packed >> 16) & 0xffff;
    }
}

// Sum partials per bin; emit deg_in (for scan) + inv_i + inv_o (inv_kernel fused).
__global__ __launch_bounds__(256) void hist_reduce(const int* __restrict__ part_in,
                                                   const int* __restrict__ part_out,
                                                   int N, int* __restrict__ deg_in,
                                                   float* __restrict__ inv_i,
                                                   float* __restrict__ inv_o) {
    int b = blockIdx.x * blockDim.x + threadIdx.x;
    if (b >= N) return;
    int di = 0, dox = 0;
#pragma unroll 4
    for (int k = 0; k < HB_CHUNKS; ++k) {
        di += part_in[(size_t)k * N + b];
        dox += part_out[(size_t)k * N + b];
    }
    deg_in[b] = di;
    inv_i[b] = rsqrtf((float)max(di, 1));
    inv_o[b] = rsqrtf((float)max(dox, 1));
}

// ---------------------------------------------------------------- 3-phase full-grid scan
#define SCAN_B 256
__global__ __launch_bounds__(SCAN_B) void scan_partial(const int* __restrict__ deg,
                                                       int* __restrict__ blockSums, int n) {
    __shared__ int sm[SCAN_B];
    int i = blockIdx.x * SCAN_B + threadIdx.x;
    int v = (i < n) ? deg[i] : 0;
    sm[threadIdx.x] = v;
    __syncthreads();
#pragma unroll
    for (int off = SCAN_B / 2; off > 0; off >>= 1) {
        if (threadIdx.x < off) sm[threadIdx.x] += sm[threadIdx.x + off];
        __syncthreads();
    }
    if (threadIdx.x == 0) blockSums[blockIdx.x] = sm[0];
}

__global__ __launch_bounds__(SCAN_B) void scan_blocksums(int* __restrict__ blockSums, int nb) {
    __shared__ int sm[SCAN_B];
    int t = threadIdx.x;
    int v = (t < nb) ? blockSums[t] : 0;
    sm[t] = v;
    __syncthreads();
#pragma unroll
    for (int off = 1; off < SCAN_B; off <<= 1) {
        int u = (t >= off) ? sm[t - off] : 0;
        __syncthreads();
        sm[t] += u;
        __syncthreads();
    }
    if (t < nb) blockSums[t] = sm[t] - v;  // exclusive
}

__global__ __launch_bounds__(SCAN_B) void scan_final(const int* __restrict__ deg,
                                                     const int* __restrict__ blockSums,
                                                     int* __restrict__ row,
                                                     int* __restrict__ cursor, int n) {
    __shared__ int sm[SCAN_B];
    int i = blockIdx.x * SCAN_B + threadIdx.x;
    int v = (i < n) ? deg[i] : 0;
    sm[threadIdx.x] = v;
    __syncthreads();
#pragma unroll
    for (int off = 1; off < SCAN_B; off <<= 1) {
        int u = (threadIdx.x >= off) ? sm[threadIdx.x - off] : 0;
        __syncthreads();
        sm[threadIdx.x] += u;
        __syncthreads();
    }
    int excl = sm[threadIdx.x] - v + blockSums[blockIdx.x];
    if (i < n) {
        row[i] = excl;
        cursor[i] = excl;
        if (i == n - 1) row[n] = excl + v;
    }
}

// ---------------------------------------------------------------- scatter into CSR
__global__ void scatter_kernel(const int* __restrict__ src, const int* __restrict__ dst,
                               int* __restrict__ cursor, int* __restrict__ csr_src, int E) {
    int e = blockIdx.x * blockDim.x + threadIdx.x;
    if (e < E) {
        int p = atomicAdd(&cursor[dst[e]], 1);
        csr_src[p] = src[e];
    }
}

// ---------------------------------------------------------------- fp32 -> bf16 bulk convert
__global__ void cvt_kernel(const float* __restrict__ in, __hip_bfloat16* __restrict__ out, int n4) {
    int i = blockIdx.x * blockDim.x + threadIdx.x;
    if (i < n4) {
        float4 v = reinterpret_cast<const float4*>(in)[i];
        __hip_bfloat16 b0 = __float2bfloat16(v.x);
        __hip_bfloat16 b1 = __float2bfloat16(v.y);
        __hip_bfloat16 b2 = __float2bfloat16(v.z);
        __hip_bfloat16 b3 = __float2bfloat16(v.w);
        ushort4 o = make_ushort4(*(unsigned short*)&b0, *(unsigned short*)&b1,
                                 *(unsigned short*)&b2, *(unsigned short*)&b3);
        reinterpret_cast<ushort4*>(out)[i] = o;
    }
}

// ---------------------------------------------------------------- fp32 [K][N] -> bf16 [N][K]
__global__ void cvt_transpose_kernel(const float* __restrict__ W, __hip_bfloat16* __restrict__ Wt,
                                     int K, int N) {
    int idx = blockIdx.x * blockDim.x + threadIdx.x;
    if (idx < K * N) {
        int k = idx / N;
        int n = idx - k * N;
        Wt[n * K + k] = __float2bfloat16(W[idx]);
    }
}

// ---------------------------------------------------------------- CSR SpMM, bf16 feat, F=128.
// One wave per node; lane handles feature pair (2*lane, 2*lane+1) loaded as one uint
// (256B per wave-instruction per source row). acc fp32; out bf16 or fp32.
__device__ __forceinline__ void bf2_unpack(unsigned int p, float& lo, float& hi) {
    lo = __uint_as_float(p << 16);
    hi = __uint_as_float(p & 0xffff0000u);
}

__global__ __launch_bounds__(256) void spmm_kernel(const __hip_bfloat16* __restrict__ feat,
                                                   const float* __restrict__ scale,
                                                   const int* __restrict__ row,
                                                   const int* __restrict__ csr_src,
                                                   __hip_bfloat16* __restrict__ out_bf,
                                                   float* __restrict__ out_f32, int N) {
    const int node = blockIdx.x * 4 + (threadIdx.x >> 6);
    if (node >= N) return;
    const int lane = threadIdx.x & 63;
    const unsigned int* fp = (const unsigned int*)feat;
    const int beg = row[node];
    const int end = row[node + 1];
    float a0 = 0.f, a1 = 0.f;
    int j = beg;
    if (scale) {
        for (; j + 4 <= end; j += 4) {
            int s0 = csr_src[j], s1 = csr_src[j + 1], s2 = csr_src[j + 2], s3 = csr_src[j + 3];
            unsigned int p0 = fp[(size_t)s0 * 64 + lane];
            unsigned int p1 = fp[(size_t)s1 * 64 + lane];
            unsigned int p2 = fp[(size_t)s2 * 64 + lane];
            unsigned int p3 = fp[(size_t)s3 * 64 + lane];
            float c0 = scale[s0], c1 = scale[s1], c2 = scale[s2], c3 = scale[s3];
            float lo, hi;
            bf2_unpack(p0, lo, hi); a0 += lo * c0; a1 += hi * c0;
            bf2_unpack(p1, lo, hi); a0 += lo * c1; a1 += hi * c1;
            bf2_unpack(p2, lo, hi); a0 += lo * c2; a1 += hi * c2;
            bf2_unpack(p3, lo, hi); a0 += lo * c3; a1 += hi * c3;
        }
        for (; j < end; ++j) {
            int s0 = csr_src[j];
            unsigned int p0 = fp[(size_t)s0 * 64 + lane];
            float c0 = scale[s0], lo, hi;
            bf2_unpack(p0, lo, hi); a0 += lo * c0; a1 += hi * c0;
        }
    } else {
        for (; j + 4 <= end; j += 4) {
            int s0 = csr_src[j], s1 = csr_src[j + 1], s2 = csr_src[j + 2], s3 = csr_src[j + 3];
            unsigned int p0 = fp[(size_t)s0 * 64 + lane];
            unsigned int p1 = fp[(size_t)s1 * 64 + lane];
            unsigned int p2 = fp[(size_t)s2 * 64 + lane];
            unsigned int p3 = fp[(size_t)s3 * 64 + lane];
            float lo, hi;
            bf2_unpack(p0, lo, hi); a0 += lo; a1 += hi;
            bf2_unpack(p1, lo, hi); a0 += lo; a1 += hi;
            bf2_unpack(p2, lo, hi); a0 += lo; a1 += hi;
            bf2_unpack(p3, lo, hi); a0 += lo; a1 += hi;
        }
        for (; j < end; ++j) {
            unsigned int p0 = fp[(size_t)csr_src[j] * 64 + lane];
            float lo, hi;
            bf2_unpack(p0, lo, hi); a0 += lo; a1 += hi;
        }
    }
    if (out_bf) {
        __hip_bfloat16 b0 = __float2bfloat16(a0);
        __hip_bfloat16 b1 = __float2bfloat16(a1);
        unsigned int packed = (unsigned int)(*(unsigned short*)&b0) |
                              ((unsigned int)(*(unsigned short*)&b1) << 16);
        ((unsigned int*)out_bf)[(size_t)node * 64 + lane] = packed;
    } else {
        float2 o = make_float2(a0, a1);
        ((float2*)out_f32)[(size_t)node * 64 + lane] = o;
    }
}

// ---------------------------------------------------------------- MFMA bf16 GEMM
// C[r][c] = epilogue( sum_k A[r][k] * Bt[c][k] )
#define GBM 128
#define GBN 128
#define GBK 32
#define LPAD 40
typedef __attribute__((ext_vector_type(4))) float floatx4;
typedef __attribute__((ext_vector_type(8))) short shortx8;

__global__ __launch_bounds__(256) void mfma_gemm_kernel(const __hip_bfloat16* __restrict__ A,
                                                        const __hip_bfloat16* __restrict__ Bt,
                                                        __hip_bfloat16* __restrict__ C,
                                                        const float* __restrict__ scaleR,
                                                        const float* __restrict__ bias,
                                                        const float* __restrict__ scaleO,
                                                        int M, int Nn, int K, int doRelu) {
    __shared__ __align__(16) __hip_bfloat16 As[GBM * LPAD];
    __shared__ __align__(16) __hip_bfloat16 Bs[GBN * LPAD];
    const int tid = threadIdx.x;
    const int bm = blockIdx.x * GBM;
    const int bn = blockIdx.y * GBN;
    const int wid = tid >> 6;
    const int lane = tid & 63;
    const int wm = (wid & 1) * 64;
    const int wn = (wid >> 1) * 64;
    const int lrow = lane & 15;
    const int quad = lane >> 4;

    floatx4 acc[4][4] = {};

    for (int k0 = 0; k0 < K; k0 += GBK) {
#pragma unroll
        for (int it = 0; it < 2; ++it) {
            int slot = tid + (it << 8);
            int r = slot >> 2;
            int c = (slot & 3) << 3;
            int gr = bm + r;
            float4 v = make_float4(0.f, 0.f, 0.f, 0.f);
            if (gr < M) v = *reinterpret_cast<const float4*>(A + (size_t)gr * K + k0 + c);
            *reinterpret_cast<float4*>(&As[r * LPAD + c]) = v;
        }
#pragma unroll
        for (int it = 0; it < 2; ++it) {
            int slot = tid + (it << 8);
            int r = slot >> 2;
            int c = (slot & 3) << 3;
            float4 v = *reinterpret_cast<const float4*>(Bt + (size_t)(bn + r) * K + k0 + c);
            *reinterpret_cast<float4*>(&Bs[r * LPAD + c]) = v;
        }
        __syncthreads();

        shortx8 af[4], bf[4];
#pragma unroll
        for (int i = 0; i < 4; ++i)
            af[i] = *reinterpret_cast<const shortx8*>(&As[(wm + i * 16 + lrow) * LPAD + quad * 8]);
#pragma unroll
        for (int i = 0; i < 4; ++i)
            bf[i] = *reinterpret_cast<const shortx8*>(&Bs[(wn + i * 16 + lrow) * LPAD + quad * 8]);
#pragma unroll
        for (int im = 0; im < 4; ++im)
#pragma unroll
            for (int in = 0; in < 4; ++in)
                acc[im][in] = __builtin_amdgcn_mfma_f32_16x16x32_bf16(af[im], bf[in], acc[im][in], 0, 0, 0);
        __syncthreads();
    }

    float bv[4];
#pragma unroll
    for (int in = 0; in < 4; ++in)
        bv[in] = bias ? bias[bn + wn + in * 16 + lrow] : 0.f;

#pragma unroll
    for (int im = 0; im < 4; ++im) {
#pragma unroll
        for (int reg = 0; reg < 4; ++reg) {
            int r = bm + wm + im * 16 + quad * 4 + reg;
            if (r >= M) continue;
            float sR = scaleR ? scaleR[r] : 1.f;
            float sO = scaleO ? scaleO[r] : 1.f;
#pragma unroll
            for (int in = 0; in < 4; ++in) {
                int c = bn + wn + in * 16 + lrow;
                float v = acc[im][in][reg] * sR + bv[in];
                if (doRelu) v = fmaxf(v, 0.f);
                v *= sO;
                C[(size_t)r * Nn + c] = __float2bfloat16(v);
            }
        }
    }
}

// ---------------------------------------------------------------- chunk-parallel pooling.
#define POOL_CHUNK 64
__global__ __launch_bounds__(128) void pool_kernel(const float* __restrict__ agg2,
                                                   const float* __restrict__ inv_i,
                                                   const float* __restrict__ b2,
                                                   const int* __restrict__ graph_id,
                                                   int n, float* __restrict__ hg_sum) {
    const int f = threadIdx.x;
    const int beg = blockIdx.x * POOL_CHUNK;
    const int end = min(beg + POOL_CHUNK, n);
    if (beg >= n) return;
    const float bias = b2[f];
    int g = graph_id[beg];
    float acc = 0.f;
    for (int i = beg; i < end; ++i) {
        int gi = graph_id[i];
        if (gi != g) {
            atomicAdd(&hg_sum[g * HID2 + f], acc);
            acc = 0.f;
            g = gi;
        }
        float v = agg2[(size_t)i * HID2 + f] * inv_i[i] + bias;
        acc += fmaxf(v, 0.f);
    }
    atomicAdd(&hg_sum[g * HID2 + f], acc);
}

// ---------------------------------------------------------------- tiny 3-layer MLP, block/graph
__device__ __forceinline__ int lower_bound_i(const int* a, int n, int key) {
    int lo = 0, hi = n;
    while (lo < hi) {
        int mid = (lo + hi) >> 1;
        if (a[mid] < key) lo = mid + 1; else hi = mid;
    }
    return lo;
}

__global__ __launch_bounds__(64) void mlp_kernel(const float* __restrict__ hg_sum,
                                                 const int* __restrict__ graph_id, int n,
                                                 const float* __restrict__ Wc1, const float* __restrict__ bc1,
                                                 const float* __restrict__ Wc2, const float* __restrict__ bc2,
                                                 const float* __restrict__ Wc3, const float* __restrict__ bc3,
                                                 float* __restrict__ out) {
    const int g = blockIdx.x;
    const int t = threadIdx.x;
    __shared__ float h[HID2];
    __shared__ float t1[12];
    __shared__ float t2[12];
    __shared__ float s_inv_cnt;
    if (t == 0) {
        int beg = lower_bound_i(graph_id, n, g);
        int end = lower_bound_i(graph_id, n, g + 1);
        int c = end - beg;
        s_inv_cnt = 1.0f / (float)max(c, 1);
    }
    __syncthreads();
    const float ic = s_inv_cnt;
    for (int i = t; i < HID2; i += 64) h[i] = hg_sum[g * HID2 + i] * ic;
    __syncthreads();
    if (t < 12) {
        float a = bc1[t];
        for (int k = 0; k < HID2; ++k) a += h[k] * Wc1[k * 12 + t];
        t1[t] = a;
    }
    __syncthreads();
    if (t < 12) {
        float a = bc2[t];
        for (int k = 0; k < 12; ++k) a += t1[k] * Wc2[k * 12 + t];
        t2[t] = a;
    }
    __syncthreads();
    if (t < 10) {
        float a = bc3[t];
        for (int k = 0; k < 12; ++k) a += t2[k] * Wc3[k * 10 + t];
        out[g * 10 + t] = a;
    }
}

// ================================================================ launch
extern "C" void kernel_launch(void* const* d_in, const int* in_sizes, int n_in,
                              void* d_out, int out_size, void* d_ws, size_t ws_size,
                              hipStream_t stream) {
    const float* x        = (const float*)d_in[0];
    const int*   src      = (const int*)d_in[1];
    const int*   dst      = (const int*)d_in[2];
    const int*   graph_id = (const int*)d_in[3];
    const float* W1       = (const float*)d_in[4];
    const float* b1       = (const float*)d_in[5];
    const float* W2       = (const float*)d_in[6];
    const float* b2       = (const float*)d_in[7];
    const float* Wc1      = (const float*)d_in[8];
    const float* bc1      = (const float*)d_in[9];
    const float* Wc2      = (const float*)d_in[10];
    const float* bc2      = (const float*)d_in[11];
    const float* Wc3      = (const float*)d_in[12];
    const float* bc3      = (const float*)d_in[13];
    float* out = (float*)d_out;

    const int N = in_sizes[0] / IN_DIM;   // 50000
    const int E = in_sizes[1];            // 800000
    const int G = out_size / 10;          // 64

    char* ws = (char*)d_ws;
    size_t off = 0;
    auto alloc = [&](size_t bytes) -> char* {
        char* p = ws + off;
        off = (off + bytes + 255) & ~(size_t)255;
        return p;
    };
    const int NB = (N + SCAN_B - 1) / SCAN_B;
    int*   deg_in  = (int*)alloc((size_t)N * 4);
    float* inv_i   = (float*)alloc((size_t)N * 4);
    float* inv_o   = (float*)alloc((size_t)N * 4);
    int*   row     = (int*)alloc((size_t)(N + 1) * 4);
    int*   cursor  = (int*)alloc((size_t)N * 4);
    int*   bsums   = (int*)alloc((size_t)NB * 4);
    int*   csr_src = (int*)alloc((size_t)E * 4);
    float* hg      = (float*)alloc((size_t)G * HID2 * 4);
    __hip_bfloat16* x_bf    = (__hip_bfloat16*)alloc((size_t)N * IN_DIM * 2);
    __hip_bfloat16* W1t     = (__hip_bfloat16*)alloc((size_t)IN_DIM * HID1 * 2);
    __hip_bfloat16* W2t     = (__hip_bfloat16*)alloc((size_t)HID1 * HID2 * 2);
    __hip_bfloat16* agg1_bf = (__hip_bfloat16*)alloc((size_t)N * IN_DIM * 2);
    __hip_bfloat16* h1_bf   = (__hip_bfloat16*)alloc((size_t)N * HID1 * 2);
    __hip_bfloat16* xw2_bf  = (__hip_bfloat16*)alloc((size_t)N * HID2 * 2);
    float* agg2    = (float*)alloc((size_t)N * HID2 * 4);

    // Histogram partials alias h1_bf (2 x HB_CHUNKS x N ints = 25.6 MB = h1_bf size);
    // h1_bf is only written later by gemm1, after hist_reduce has consumed them.
    int* part_in  = (int*)h1_bf;
    int* part_out = part_in + (size_t)HB_CHUNKS * N;

    hipMemsetAsync(hg, 0, (size_t)G * HID2 * 4, stream);

    // graph structure (no global atomics for degrees)
    const int chunk_size = (E + HB_CHUNKS - 1) / HB_CHUNKS;   // 12500, <= 65535 required
    const int n_ranges = (N + HB_BINS - 1) / HB_BINS;         // 2
    hist_count<<<dim3(HB_CHUNKS, n_ranges, 2), 256, 0, stream>>>(src, dst, E, chunk_size,
                                                                 part_in, part_out, N);
    hist_reduce<<<(N + 255) / 256, 256, 0, stream>>>(part_in, part_out, N, deg_in, inv_i, inv_o);
    scan_partial<<<NB, SCAN_B, 0, stream>>>(deg_in, bsums, N);
    scan_blocksums<<<1, SCAN_B, 0, stream>>>(bsums, NB);
    scan_final<<<NB, SCAN_B, 0, stream>>>(deg_in, bsums, row, cursor, N);
    scatter_kernel<<<(E + 255) / 256, 256, 0, stream>>>(src, dst, cursor, csr_src, E);

    // bf16 conversions
    cvt_kernel<<<(N * IN_DIM / 4 + 255) / 256, 256, 0, stream>>>(x, x_bf, N * IN_DIM / 4);
    cvt_transpose_kernel<<<(IN_DIM * HID1 + 255) / 256, 256, 0, stream>>>(W1, W1t, IN_DIM, HID1);
    cvt_transpose_kernel<<<(HID1 * HID2 + 255) / 256, 256, 0, stream>>>(W2, W2t, HID1, HID2);

    // Layer 1, aggregate-first: agg1 = A * (x * inv_o); h1 = relu(inv_i*(agg1@W1) + b1) * inv_o
    spmm_kernel<<<(N + 3) / 4, 256, 0, stream>>>(x_bf, inv_o, row, csr_src, agg1_bf, nullptr, N);
    mfma_gemm_kernel<<<dim3((N + GBM - 1) / GBM, HID1 / GBN), 256, 0, stream>>>(
        agg1_bf, W1t, h1_bf, inv_i, b1, inv_o, N, HID1, IN_DIM, 1);

    // Layer 2, weight-first: xw2 = h1 @ W2 (h1 carries inv_o); agg2 = A * xw2
    mfma_gemm_kernel<<<dim3((N + GBM - 1) / GBM, HID2 / GBN), 256, 0, stream>>>(
        h1_bf, W2t, xw2_bf, nullptr, nullptr, nullptr, N, HID2, HID1, 0);
    spmm_kernel<<<(N + 3) / 4, 256, 0, stream>>>(xw2_bf, nullptr, row, csr_src, nullptr, agg2, N);

    // Pool (fused relu(agg2*inv_i+b2), chunk-parallel) + MLP (fused mean-divide)
    pool_kernel<<<(N + POOL_CHUNK - 1) / POOL_CHUNK, 128, 0, stream>>>(agg2, inv_i, b2, graph_id, N, hg);
    mlp_kernel<<<G, 64, 0, stream>>>(hg, graph_id, N, Wc1, bc1, Wc2, bc2, Wc3, bc3, out);
}

// Round 6
// 305.661 us; speedup vs baseline: 2.5086x; 1.0452x over previous
//
#include <hip/hip_runtime.h>
#include <hip/hip_bf16.h>

#define IN_DIM 128
#define HID1 256
#define HID2 128

// ---------------------------------------------------------------- privatized histogram
#define HB_BINS 25000
#define HB_WORDS 12500
#define HB_CHUNKS 64
__global__ __launch_bounds__(256) void hist_count(const int* __restrict__ src,
                                                  const int* __restrict__ dst,
                                                  int E, int chunk_size,
                                                  int* __restrict__ part_in,
                                                  int* __restrict__ part_out, int N) {
    __shared__ int sm[HB_WORDS];
    const int* idx = (blockIdx.z == 0) ? dst : src;
    int* part = (blockIdx.z == 0) ? part_in : part_out;
    const int base = blockIdx.y * HB_BINS;
    const int ebeg = blockIdx.x * chunk_size;
    const int eend = min(ebeg + chunk_size, E);
    for (int w = threadIdx.x; w < HB_WORDS; w += 256) sm[w] = 0;
    __syncthreads();
    for (int e = ebeg + threadIdx.x; e < eend; e += 256) {
        int v = idx[e] - base;
        if ((unsigned)v < (unsigned)HB_BINS)
            atomicAdd(&sm[v >> 1], 1 << ((v & 1) * 16));
    }
    __syncthreads();
    const int nb = min(HB_BINS, N - base);
    int* dp = part + (size_t)blockIdx.x * N + base;
    for (int w = threadIdx.x; 2 * w < nb; w += 256) {
        int packed = sm[w];
        int b = 2 * w;
        dp[b] = packed & 0xffff;
        if (b + 1 < nb) dp[b + 1] = (packed >> 16) & 0xffff;
    }
}

__global__ __launch_bounds__(256) void hist_reduce(const int* __restrict__ part_in,
                                                   const int* __restrict__ part_out,
                                                   int N, int* __restrict__ deg_in,
                                                   float* __restrict__ inv_i,
                                                   float* __restrict__ inv_o) {
    int b = blockIdx.x * blockDim.x + threadIdx.x;
    if (b >= N) return;
    int di = 0, dox = 0;
#pragma unroll 4
    for (int k = 0; k < HB_CHUNKS; ++k) {
        di += part_in[(size_t)k * N + b];
        dox += part_out[(size_t)k * N + b];
    }
    deg_in[b] = di;
    inv_i[b] = rsqrtf((float)max(di, 1));
    inv_o[b] = rsqrtf((float)max(dox, 1));
}

// ---------------------------------------------------------------- 3-phase full-grid scan
#define SCAN_B 256
__global__ __launch_bounds__(SCAN_B) void scan_partial(const int* __restrict__ deg,
                                                       int* __restrict__ blockSums, int n) {
    __shared__ int sm[SCAN_B];
    int i = blockIdx.x * SCAN_B + threadIdx.x;
    int v = (i < n) ? deg[i] : 0;
    sm[threadIdx.x] = v;
    __syncthreads();
#pragma unroll
    for (int off = SCAN_B / 2; off > 0; off >>= 1) {
        if (threadIdx.x < off) sm[threadIdx.x] += sm[threadIdx.x + off];
        __syncthreads();
    }
    if (threadIdx.x == 0) blockSums[blockIdx.x] = sm[0];
}

__global__ __launch_bounds__(SCAN_B) void scan_blocksums(int* __restrict__ blockSums, int nb) {
    __shared__ int sm[SCAN_B];
    int t = threadIdx.x;
    int v = (t < nb) ? blockSums[t] : 0;
    sm[t] = v;
    __syncthreads();
#pragma unroll
    for (int off = 1; off < SCAN_B; off <<= 1) {
        int u = (t >= off) ? sm[t - off] : 0;
        __syncthreads();
        sm[t] += u;
        __syncthreads();
    }
    if (t < nb) blockSums[t] = sm[t] - v;  // exclusive
}

__global__ __launch_bounds__(SCAN_B) void scan_final(const int* __restrict__ deg,
                                                     const int* __restrict__ blockSums,
                                                     int* __restrict__ row, int n) {
    __shared__ int sm[SCAN_B];
    int i = blockIdx.x * SCAN_B + threadIdx.x;
    int v = (i < n) ? deg[i] : 0;
    sm[threadIdx.x] = v;
    __syncthreads();
#pragma unroll
    for (int off = 1; off < SCAN_B; off <<= 1) {
        int u = (threadIdx.x >= off) ? sm[threadIdx.x - off] : 0;
        __syncthreads();
        sm[threadIdx.x] += u;
        __syncthreads();
    }
    int excl = sm[threadIdx.x] - v + blockSums[blockIdx.x];
    if (i < n) {
        row[i] = excl;
        if (i == n - 1) row[n] = excl + v;
    }
}

// ---------------------------------------------------------------- two-pass locality scatter
// Buckets of 256 nodes (196 buckets); 256 edge-chunks. Every written region is
// block-exclusive so XCD L2 merges scattered writes into full-line writebacks.
#define BK_SHIFT 8
#define NBUCK 196
#define NCHUNK 256
__global__ __launch_bounds__(256) void coarse_hist(const int* __restrict__ dst, int E,
                                                   int chunk_size, int* __restrict__ ccnt) {
    __shared__ int cnt[NBUCK];
    for (int i = threadIdx.x; i < NBUCK; i += 256) cnt[i] = 0;
    __syncthreads();
    int ebeg = blockIdx.x * chunk_size, eend = min(ebeg + chunk_size, E);
    for (int e = ebeg + threadIdx.x; e < eend; e += 256)
        atomicAdd(&cnt[dst[e] >> BK_SHIFT], 1);
    __syncthreads();
    for (int i = threadIdx.x; i < NBUCK; i += 256) ccnt[blockIdx.x * NBUCK + i] = cnt[i];
}

// block per bucket: exclusive scan of counts over 256 chunks, anchored at row[b*256]
__global__ __launch_bounds__(NCHUNK) void coarse_off(const int* __restrict__ ccnt,
                                                     const int* __restrict__ row, int N,
                                                     int* __restrict__ coff) {
    __shared__ int sm[NCHUNK];
    int b = blockIdx.x, t = threadIdx.x;
    int v = ccnt[t * NBUCK + b];
    sm[t] = v;
    __syncthreads();
#pragma unroll
    for (int off = 1; off < NCHUNK; off <<= 1) {
        int u = (t >= off) ? sm[t - off] : 0;
        __syncthreads();
        sm[t] += u;
        __syncthreads();
    }
    int base = row[min(b << BK_SHIFT, N)];
    coff[t * NBUCK + b] = base + sm[t] - v;
}

// pass A: chunk-block scatters (src,dst) pairs into its private per-bucket segments
__global__ __launch_bounds__(256) void scat_a(const int* __restrict__ src,
                                              const int* __restrict__ dst, int E,
                                              int chunk_size, const int* __restrict__ coff,
                                              int2* __restrict__ pairs) {
    __shared__ int lcur[NBUCK];
    for (int i = threadIdx.x; i < NBUCK; i += 256) lcur[i] = coff[blockIdx.x * NBUCK + i];
    __syncthreads();
    int ebeg = blockIdx.x * chunk_size, eend = min(ebeg + chunk_size, E);
    for (int e = ebeg + threadIdx.x; e < eend; e += 256) {
        int d = dst[e];
        int p = atomicAdd(&lcur[d >> BK_SHIFT], 1);
        pairs[p] = make_int2(src[e], d);
    }
}

// pass B: bucket-block places src at final CSR positions (exclusive 256-node span)
__global__ __launch_bounds__(256) void scat_b(const int2* __restrict__ pairs,
                                              const int* __restrict__ row, int N,
                                              int* __restrict__ csr_src) {
    __shared__ int cur[1 << BK_SHIFT];
    const int nb0 = blockIdx.x << BK_SHIFT;
    const int nb1 = min(nb0 + (1 << BK_SHIFT), N);
    if (nb0 >= N) return;
    for (int i = threadIdx.x; i < nb1 - nb0; i += 256) cur[i] = row[nb0 + i];
    __syncthreads();
    const int beg = row[nb0], end = row[nb1];
    for (int j = beg + threadIdx.x; j < end; j += 256) {
        int2 pr = pairs[j];
        int p = atomicAdd(&cur[pr.y - nb0], 1);
        csr_src[p] = pr.x;
    }
}

// ---------------------------------------------------------------- fp32 -> bf16 bulk convert
__global__ void cvt_kernel(const float* __restrict__ in, __hip_bfloat16* __restrict__ out, int n4) {
    int i = blockIdx.x * blockDim.x + threadIdx.x;
    if (i < n4) {
        float4 v = reinterpret_cast<const float4*>(in)[i];
        __hip_bfloat16 b0 = __float2bfloat16(v.x);
        __hip_bfloat16 b1 = __float2bfloat16(v.y);
        __hip_bfloat16 b2 = __float2bfloat16(v.z);
        __hip_bfloat16 b3 = __float2bfloat16(v.w);
        ushort4 o = make_ushort4(*(unsigned short*)&b0, *(unsigned short*)&b1,
                                 *(unsigned short*)&b2, *(unsigned short*)&b3);
        reinterpret_cast<ushort4*>(out)[i] = o;
    }
}

// ---------------------------------------------------------------- fp32 [K][N] -> bf16 [N][K]
__global__ void cvt_transpose_kernel(const float* __restrict__ W, __hip_bfloat16* __restrict__ Wt,
                                     int K, int N) {
    int idx = blockIdx.x * blockDim.x + threadIdx.x;
    if (idx < K * N) {
        int k = idx / N;
        int n = idx - k * N;
        Wt[n * K + k] = __float2bfloat16(W[idx]);
    }
}

// ---------------------------------------------------------------- CSR SpMM, bf16 feat, F=128.
__device__ __forceinline__ void bf2_unpack(unsigned int p, float& lo, float& hi) {
    lo = __uint_as_float(p << 16);
    hi = __uint_as_float(p & 0xffff0000u);
}

__global__ __launch_bounds__(256) void spmm_kernel(const __hip_bfloat16* __restrict__ feat,
                                                   const float* __restrict__ scale,
                                                   const int* __restrict__ row,
                                                   const int* __restrict__ csr_src,
                                                   __hip_bfloat16* __restrict__ out_bf,
                                                   float* __restrict__ out_f32, int N) {
    const int node = blockIdx.x * 4 + (threadIdx.x >> 6);
    if (node >= N) return;
    const int lane = threadIdx.x & 63;
    const unsigned int* fp = (const unsigned int*)feat;
    const int beg = row[node];
    const int end = row[node + 1];
    float a0 = 0.f, a1 = 0.f;
    int j = beg;
    if (scale) {
        for (; j + 4 <= end; j += 4) {
            int s0 = csr_src[j], s1 = csr_src[j + 1], s2 = csr_src[j + 2], s3 = csr_src[j + 3];
            unsigned int p0 = fp[(size_t)s0 * 64 + lane];
            unsigned int p1 = fp[(size_t)s1 * 64 + lane];
            unsigned int p2 = fp[(size_t)s2 * 64 + lane];
            unsigned int p3 = fp[(size_t)s3 * 64 + lane];
            float c0 = scale[s0], c1 = scale[s1], c2 = scale[s2], c3 = scale[s3];
            float lo, hi;
            bf2_unpack(p0, lo, hi); a0 += lo * c0; a1 += hi * c0;
            bf2_unpack(p1, lo, hi); a0 += lo * c1; a1 += hi * c1;
            bf2_unpack(p2, lo, hi); a0 += lo * c2; a1 += hi * c2;
            bf2_unpack(p3, lo, hi); a0 += lo * c3; a1 += hi * c3;
        }
        for (; j < end; ++j) {
            int s0 = csr_src[j];
            unsigned int p0 = fp[(size_t)s0 * 64 + lane];
            float c0 = scale[s0], lo, hi;
            bf2_unpack(p0, lo, hi); a0 += lo * c0; a1 += hi * c0;
        }
    } else {
        for (; j + 4 <= end; j += 4) {
            int s0 = csr_src[j], s1 = csr_src[j + 1], s2 = csr_src[j + 2], s3 = csr_src[j + 3];
            unsigned int p0 = fp[(size_t)s0 * 64 + lane];
            unsigned int p1 = fp[(size_t)s1 * 64 + lane];
            unsigned int p2 = fp[(size_t)s2 * 64 + lane];
            unsigned int p3 = fp[(size_t)s3 * 64 + lane];
            float lo, hi;
            bf2_unpack(p0, lo, hi); a0 += lo; a1 += hi;
            bf2_unpack(p1, lo, hi); a0 += lo; a1 += hi;
            bf2_unpack(p2, lo, hi); a0 += lo; a1 += hi;
            bf2_unpack(p3, lo, hi); a0 += lo; a1 += hi;
        }
        for (; j < end; ++j) {
            unsigned int p0 = fp[(size_t)csr_src[j] * 64 + lane];
            float lo, hi;
            bf2_unpack(p0, lo, hi); a0 += lo; a1 += hi;
        }
    }
    if (out_bf) {
        __hip_bfloat16 b0 = __float2bfloat16(a0);
        __hip_bfloat16 b1 = __float2bfloat16(a1);
        unsigned int packed = (unsigned int)(*(unsigned short*)&b0) |
                              ((unsigned int)(*(unsigned short*)&b1) << 16);
        ((unsigned int*)out_bf)[(size_t)node * 64 + lane] = packed;
    } else {
        float2 o = make_float2(a0, a1);
        ((float2*)out_f32)[(size_t)node * 64 + lane] = o;
    }
}

// ---------------------------------------------------------------- MFMA bf16 GEMM
#define GBM 128
#define GBN 128
#define GBK 32
#define LPAD 40
typedef __attribute__((ext_vector_type(4))) float floatx4;
typedef __attribute__((ext_vector_type(8))) short shortx8;

__global__ __launch_bounds__(256) void mfma_gemm_kernel(const __hip_bfloat16* __restrict__ A,
                                                        const __hip_bfloat16* __restrict__ Bt,
                                                        __hip_bfloat16* __restrict__ C,
                                                        const float* __restrict__ scaleR,
                                                        const float* __restrict__ bias,
                                                        const float* __restrict__ scaleO,
                                                        int M, int Nn, int K, int doRelu) {
    __shared__ __align__(16) __hip_bfloat16 As[GBM * LPAD];
    __shared__ __align__(16) __hip_bfloat16 Bs[GBN * LPAD];
    const int tid = threadIdx.x;
    const int bm = blockIdx.x * GBM;
    const int bn = blockIdx.y * GBN;
    const int wid = tid >> 6;
    const int lane = tid & 63;
    const int wm = (wid & 1) * 64;
    const int wn = (wid >> 1) * 64;
    const int lrow = lane & 15;
    const int quad = lane >> 4;

    floatx4 acc[4][4] = {};

    for (int k0 = 0; k0 < K; k0 += GBK) {
#pragma unroll
        for (int it = 0; it < 2; ++it) {
            int slot = tid + (it << 8);
            int r = slot >> 2;
            int c = (slot & 3) << 3;
            int gr = bm + r;
            float4 v = make_float4(0.f, 0.f, 0.f, 0.f);
            if (gr < M) v = *reinterpret_cast<const float4*>(A + (size_t)gr * K + k0 + c);
            *reinterpret_cast<float4*>(&As[r * LPAD + c]) = v;
        }
#pragma unroll
        for (int it = 0; it < 2; ++it) {
            int slot = tid + (it << 8);
            int r = slot >> 2;
            int c = (slot & 3) << 3;
            float4 v = *reinterpret_cast<const float4*>(Bt + (size_t)(bn + r) * K + k0 + c);
            *reinterpret_cast<float4*>(&Bs[r * LPAD + c]) = v;
        }
        __syncthreads();

        shortx8 af[4], bf[4];
#pragma unroll
        for (int i = 0; i < 4; ++i)
            af[i] = *reinterpret_cast<const shortx8*>(&As[(wm + i * 16 + lrow) * LPAD + quad * 8]);
#pragma unroll
        for (int i = 0; i < 4; ++i)
            bf[i] = *reinterpret_cast<const shortx8*>(&Bs[(wn + i * 16 + lrow) * LPAD + quad * 8]);
#pragma unroll
        for (int im = 0; im < 4; ++im)
#pragma unroll
            for (int in = 0; in < 4; ++in)
                acc[im][in] = __builtin_amdgcn_mfma_f32_16x16x32_bf16(af[im], bf[in], acc[im][in], 0, 0, 0);
        __syncthreads();
    }

    float bv[4];
#pragma unroll
    for (int in = 0; in < 4; ++in)
        bv[in] = bias ? bias[bn + wn + in * 16 + lrow] : 0.f;

#pragma unroll
    for (int im = 0; im < 4; ++im) {
#pragma unroll
        for (int reg = 0; reg < 4; ++reg) {
            int r = bm + wm + im * 16 + quad * 4 + reg;
            if (r >= M) continue;
            float sR = scaleR ? scaleR[r] : 1.f;
            float sO = scaleO ? scaleO[r] : 1.f;
#pragma unroll
            for (int in = 0; in < 4; ++in) {
                int c = bn + wn + in * 16 + lrow;
                float v = acc[im][in][reg] * sR + bv[in];
                if (doRelu) v = fmaxf(v, 0.f);
                v *= sO;
                C[(size_t)r * Nn + c] = __float2bfloat16(v);
            }
        }
    }
}

// ---------------------------------------------------------------- chunk-parallel pooling.
#define POOL_CHUNK 64
__global__ __launch_bounds__(128) void pool_kernel(const float* __restrict__ agg2,
                                                   const float* __restrict__ inv_i,
                                                   const float* __restrict__ b2,
                                                   const int* __restrict__ graph_id,
                                                   int n, float* __restrict__ hg_sum) {
    const int f = threadIdx.x;
    const int beg = blockIdx.x * POOL_CHUNK;
    const int end = min(beg + POOL_CHUNK, n);
    if (beg >= n) return;
    const float bias = b2[f];
    int g = graph_id[beg];
    float acc = 0.f;
    for (int i = beg; i < end; ++i) {
        int gi = graph_id[i];
        if (gi != g) {
            atomicAdd(&hg_sum[g * HID2 + f], acc);
            acc = 0.f;
            g = gi;
        }
        float v = agg2[(size_t)i * HID2 + f] * inv_i[i] + bias;
        acc += fmaxf(v, 0.f);
    }
    atomicAdd(&hg_sum[g * HID2 + f], acc);
}

// ---------------------------------------------------------------- tiny 3-layer MLP, block/graph
__device__ __forceinline__ int lower_bound_i(const int* a, int n, int key) {
    int lo = 0, hi = n;
    while (lo < hi) {
        int mid = (lo + hi) >> 1;
        if (a[mid] < key) lo = mid + 1; else hi = mid;
    }
    return lo;
}

__global__ __launch_bounds__(64) void mlp_kernel(const float* __restrict__ hg_sum,
                                                 const int* __restrict__ graph_id, int n,
                                                 const float* __restrict__ Wc1, const float* __restrict__ bc1,
                                                 const float* __restrict__ Wc2, const float* __restrict__ bc2,
                                                 const float* __restrict__ Wc3, const float* __restrict__ bc3,
                                                 float* __restrict__ out) {
    const int g = blockIdx.x;
    const int t = threadIdx.x;
    __shared__ float h[HID2];
    __shared__ float t1[12];
    __shared__ float t2[12];
    __shared__ float s_inv_cnt;
    if (t == 0) {
        int beg = lower_bound_i(graph_id, n, g);
        int end = lower_bound_i(graph_id, n, g + 1);
        int c = end - beg;
        s_inv_cnt = 1.0f / (float)max(c, 1);
    }
    __syncthreads();
    const float ic = s_inv_cnt;
    for (int i = t; i < HID2; i += 64) h[i] = hg_sum[g * HID2 + i] * ic;
    __syncthreads();
    if (t < 12) {
        float a = bc1[t];
        for (int k = 0; k < HID2; ++k) a += h[k] * Wc1[k * 12 + t];
        t1[t] = a;
    }
    __syncthreads();
    if (t < 12) {
        float a = bc2[t];
        for (int k = 0; k < 12; ++k) a += t1[k] * Wc2[k * 12 + t];
        t2[t] = a;
    }
    __syncthreads();
    if (t < 10) {
        float a = bc3[t];
        for (int k = 0; k < 12; ++k) a += t2[k] * Wc3[k * 10 + t];
        out[g * 10 + t] = a;
    }
}

// ================================================================ launch
extern "C" void kernel_launch(void* const* d_in, const int* in_sizes, int n_in,
                              void* d_out, int out_size, void* d_ws, size_t ws_size,
                              hipStream_t stream) {
    const float* x        = (const float*)d_in[0];
    const int*   src      = (const int*)d_in[1];
    const int*   dst      = (const int*)d_in[2];
    const int*   graph_id = (const int*)d_in[3];
    const float* W1       = (const float*)d_in[4];
    const float* b1       = (const float*)d_in[5];
    const float* W2       = (const float*)d_in[6];
    const float* b2       = (const float*)d_in[7];
    const float* Wc1      = (const float*)d_in[8];
    const float* bc1      = (const float*)d_in[9];
    const float* Wc2      = (const float*)d_in[10];
    const float* bc2      = (const float*)d_in[11];
    const float* Wc3      = (const float*)d_in[12];
    const float* bc3      = (const float*)d_in[13];
    float* out = (float*)d_out;

    const int N = in_sizes[0] / IN_DIM;   // 50000
    const int E = in_sizes[1];            // 800000
    const int G = out_size / 10;          // 64

    char* ws = (char*)d_ws;
    size_t off = 0;
    auto alloc = [&](size_t bytes) -> char* {
        char* p = ws + off;
        off = (off + bytes + 255) & ~(size_t)255;
        return p;
    };
    const int NB = (N + SCAN_B - 1) / SCAN_B;
    int*   deg_in  = (int*)alloc((size_t)N * 4);
    float* inv_i   = (float*)alloc((size_t)N * 4);
    float* inv_o   = (float*)alloc((size_t)N * 4);
    int*   row     = (int*)alloc((size_t)(N + 1) * 4);
    int*   bsums   = (int*)alloc((size_t)NB * 4);
    int*   ccnt    = (int*)alloc((size_t)NCHUNK * NBUCK * 4);
    int*   coff    = (int*)alloc((size_t)NCHUNK * NBUCK * 4);
    int2*  pairs   = (int2*)alloc((size_t)E * 8);
    int*   csr_src = (int*)alloc((size_t)E * 4);
    float* hg      = (float*)alloc((size_t)G * HID2 * 4);
    __hip_bfloat16* x_bf    = (__hip_bfloat16*)alloc((size_t)N * IN_DIM * 2);
    __hip_bfloat16* W1t     = (__hip_bfloat16*)alloc((size_t)IN_DIM * HID1 * 2);
    __hip_bfloat16* W2t     = (__hip_bfloat16*)alloc((size_t)HID1 * HID2 * 2);
    __hip_bfloat16* agg1_bf = (__hip_bfloat16*)alloc((size_t)N * IN_DIM * 2);
    __hip_bfloat16* h1_bf   = (__hip_bfloat16*)alloc((size_t)N * HID1 * 2);
    __hip_bfloat16* xw2_bf  = (__hip_bfloat16*)alloc((size_t)N * HID2 * 2);
    float* agg2    = (float*)alloc((size_t)N * HID2 * 4);

    // Histogram partials alias h1_bf (written later by gemm1, after hist_reduce consumed them)
    int* part_in  = (int*)h1_bf;
    int* part_out = part_in + (size_t)HB_CHUNKS * N;

    hipMemsetAsync(hg, 0, (size_t)G * HID2 * 4, stream);

    // degrees (privatized, no global atomics)
    const int hchunk = (E + HB_CHUNKS - 1) / HB_CHUNKS;
    const int n_ranges = (N + HB_BINS - 1) / HB_BINS;
    hist_count<<<dim3(HB_CHUNKS, n_ranges, 2), 256, 0, stream>>>(src, dst, E, hchunk,
                                                                 part_in, part_out, N);
    hist_reduce<<<(N + 255) / 256, 256, 0, stream>>>(part_in, part_out, N, deg_in, inv_i, inv_o);
    scan_partial<<<NB, SCAN_B, 0, stream>>>(deg_in, bsums, N);
    scan_blocksums<<<1, SCAN_B, 0, stream>>>(bsums, NB);
    scan_final<<<NB, SCAN_B, 0, stream>>>(deg_in, bsums, row, N);

    // CSR build: two-pass locality scatter (no global atomics, block-exclusive writes)
    const int schunk = (E + NCHUNK - 1) / NCHUNK;
    coarse_hist<<<NCHUNK, 256, 0, stream>>>(dst, E, schunk, ccnt);
    coarse_off<<<NBUCK, NCHUNK, 0, stream>>>(ccnt, row, N, coff);
    scat_a<<<NCHUNK, 256, 0, stream>>>(src, dst, E, schunk, coff, pairs);
    scat_b<<<NBUCK, 256, 0, stream>>>(pairs, row, N, csr_src);

    // bf16 conversions
    cvt_kernel<<<(N * IN_DIM / 4 + 255) / 256, 256, 0, stream>>>(x, x_bf, N * IN_DIM / 4);
    cvt_transpose_kernel<<<(IN_DIM * HID1 + 255) / 256, 256, 0, stream>>>(W1, W1t, IN_DIM, HID1);
    cvt_transpose_kernel<<<(HID1 * HID2 + 255) / 256, 256, 0, stream>>>(W2, W2t, HID1, HID2);

    // Layer 1, aggregate-first: agg1 = A * (x * inv_o); h1 = relu(inv_i*(agg1@W1) + b1) * inv_o
    spmm_kernel<<<(N + 3) / 4, 256, 0, stream>>>(x_bf, inv_o, row, csr_src, agg1_bf, nullptr, N);
    mfma_gemm_kernel<<<dim3((N + GBM - 1) / GBM, HID1 / GBN), 256, 0, stream>>>(
        agg1_bf, W1t, h1_bf, inv_i, b1, inv_o, N, HID1, IN_DIM, 1);

    // Layer 2, weight-first: xw2 = h1 @ W2 (h1 carries inv_o); agg2 = A * xw2
    mfma_gemm_kernel<<<dim3((N + GBM - 1) / GBM, HID2 / GBN), 256, 0, stream>>>(
        h1_bf, W2t, xw2_bf, nullptr, nullptr, nullptr, N, HID2, HID1, 0);
    spmm_kernel<<<(N + 3) / 4, 256, 0, stream>>>(xw2_bf, nullptr, row, csr_src, nullptr, agg2, N);

    // Pool (fused relu(agg2*inv_i+b2), chunk-parallel) + MLP (fused mean-divide)
    pool_kernel<<<(N + POOL_CHUNK - 1) / POOL_CHUNK, 128, 0, stream>>>(agg2, inv_i, b2, graph_id, N, hg);
    mlp_kernel<<<G, 64, 0, stream>>>(hg, graph_id, N, Wc1, bc1, Wc2, bc2, Wc3, bc3, out);
}